// Round 6
// baseline (568.009 us; speedup 1.0000x reference)
//
#include <hip/hip_runtime.h>
#include <hip/hip_bf16.h>
#include <math.h>

typedef __hip_bfloat16 bf16;
typedef unsigned short u16;
typedef __attribute__((ext_vector_type(8))) short short8;
typedef __attribute__((ext_vector_type(4))) float f32x4;

#define NTOK 4096
#define DD   512
#define EE   8
#define DE   4096
#define HH   1024
#define OUTD 512
#define ATOT 8192
#define APAD 8320
#define MAXT 72
#define FCAP 1024
#define DMARGIN 1e-4
#define RSPLIT 4   // j-chunks per (token,expert) rescue pair

struct Tile { int e, row0, rows; };

__device__ __forceinline__ float b2f(u16 u){ return __uint_as_float(((unsigned)u)<<16); }

__device__ __forceinline__ float gelu_f(float x){
  return 0.5f * x * (1.0f + erff(x * 0.7071067811865476f));
}

__device__ __forceinline__ void gl2lds(const bf16* g, bf16* l){
  __builtin_amdgcn_global_load_lds((const __attribute__((address_space(1))) void*)g,
                                   (__attribute__((address_space(3))) void*)l, 16, 0, 0);
}

__device__ __forceinline__ f32x4 mfma16(short8 a, short8 b, f32x4 c){
  return __builtin_amdgcn_mfma_f32_16x16x32_bf16(a, b, c, 0, 0, 0);
}

// 128x128 tile, BK=32, 256 threads (4 waves, 64x64 quadrants, 4x4 mfma 16x16x32).
// LDS: row-major 32/row, XOR-swizzled 8-elem chunk (slot = kq ^ ((row>>1)&3)):
// coalesced staging (4 lanes cover one row's 64B) AND conflict-free ds_read_b128.
// 2-phase register-prefetch schedule (R2-proven, ~770 TF = ~85% of the 128²
// 2-barrier structural ceiling): read tile k into regs, re-stage LDS with tile
// k+1 while MFMAs consume the regs.
template<bool GATHER>
__device__ __forceinline__ void kloop(const bf16* __restrict__ A, int lda,
                                      const int* __restrict__ rowmap, int m0,
                                      const bf16* __restrict__ BT, int ldb, int n0,
                                      int K, bf16* As, bf16* Bs, f32x4 acc[4][4]){
  const int t = threadIdx.x;
  const int r = t>>2;
  const int sw = (t&3) ^ ((t>>3)&3);
  int ar0 = m0 + r, ar1 = m0 + 64 + r;
  if (GATHER){
    ar0 = rowmap[ar0 < ATOT ? ar0 : ATOT-1];
    ar1 = rowmap[ar1 < ATOT ? ar1 : ATOT-1];
  }
  const bf16* ap0 = A + (long)ar0*lda + sw*8;
  const bf16* ap1 = A + (long)ar1*lda + sw*8;
  const bf16* bp0 = BT + (long)(n0 + r)*ldb + sw*8;
  const bf16* bp1 = bp0 + (long)64*ldb;
  const int wave = t>>6, lane = t&63;
  const int qr = wave>>1, qc = wave&1, ln = lane&15, kq = lane>>4;
  const int slot = kq ^ ((ln>>1)&3);
  const bf16* ard = As + (qr*64 + ln)*32 + slot*8;
  const bf16* brd = Bs + (qc*64 + ln)*32 + slot*8;
  // prologue: stage k0 = 0
  gl2lds(ap0, As + t*8);
  gl2lds(ap1, As + 2048 + t*8);
  gl2lds(bp0, Bs + t*8);
  gl2lds(bp1, Bs + 2048 + t*8);
  for (int k0 = 0; k0 < K; k0 += 32){
    __syncthreads();                       // stage k0 landed (vmcnt drain)
    short8 a[4], b[4];
    #pragma unroll
    for (int i=0;i<4;i++) a[i] = *(const short8*)(ard + i*512);
    #pragma unroll
    for (int j=0;j<4;j++) b[j] = *(const short8*)(brd + j*512);
    __syncthreads();                       // reads done; LDS free for next stage
    int k1 = k0 + 32;
    if (k1 < K){
      gl2lds(ap0 + k1, As + t*8);
      gl2lds(ap1 + k1, As + 2048 + t*8);
      gl2lds(bp0 + k1, Bs + t*8);
      gl2lds(bp1 + k1, Bs + 2048 + t*8);
    }
    #pragma unroll
    for (int i=0;i<4;i++)
      #pragma unroll
      for (int j=0;j<4;j++)
        acc[i][j] = mfma16(a[i], b[j], acc[i][j]);
  }
}

// fused 2x2 split k-loop: stages Ah,Am,Bh,Bm once per k-chunk, accumulates
// hh + hm + mh in one pass; same 2-phase register-prefetch schedule.
__device__ __forceinline__ void kloop2(const bf16* __restrict__ A0, const bf16* __restrict__ A1,
                                       int lda, int m0,
                                       const bf16* __restrict__ B0, const bf16* __restrict__ B1,
                                       int ldb, int n0, int K,
                                       bf16* As0, bf16* As1, bf16* Bs0, bf16* Bs1,
                                       f32x4 acc[4][4]){
  const int t = threadIdx.x;
  const int r = t>>2;
  const int sw = (t&3) ^ ((t>>3)&3);
  const long aoff0 = (long)(m0 + r)*lda + sw*8;
  const long aoff1 = (long)(m0 + 64 + r)*lda + sw*8;
  const long boff0 = (long)(n0 + r)*ldb + sw*8;
  const long boff1 = boff0 + (long)64*ldb;
  const int wave = t>>6, lane = t&63;
  const int qr = wave>>1, qc = wave&1, ln = lane&15, kq = lane>>4;
  const int slot = kq ^ ((ln>>1)&3);
  const int ao = (qr*64 + ln)*32 + slot*8;
  const int bo = (qc*64 + ln)*32 + slot*8;
  // prologue: stage k0 = 0
  gl2lds(A0 + aoff0, As0 + t*8);
  gl2lds(A0 + aoff1, As0 + 2048 + t*8);
  gl2lds(A1 + aoff0, As1 + t*8);
  gl2lds(A1 + aoff1, As1 + 2048 + t*8);
  gl2lds(B0 + boff0, Bs0 + t*8);
  gl2lds(B0 + boff1, Bs0 + 2048 + t*8);
  gl2lds(B1 + boff0, Bs1 + t*8);
  gl2lds(B1 + boff1, Bs1 + 2048 + t*8);
  for (int k0 = 0; k0 < K; k0 += 32){
    __syncthreads();
    short8 a0[4], a1[4], b0[4], b1[4];
    #pragma unroll
    for (int i=0;i<4;i++){
      a0[i] = *(const short8*)(As0 + ao + i*512);
      a1[i] = *(const short8*)(As1 + ao + i*512);
    }
    #pragma unroll
    for (int j=0;j<4;j++){
      b0[j] = *(const short8*)(Bs0 + bo + j*512);
      b1[j] = *(const short8*)(Bs1 + bo + j*512);
    }
    __syncthreads();
    int k1 = k0 + 32;
    if (k1 < K){
      gl2lds(A0 + aoff0 + k1, As0 + t*8);
      gl2lds(A0 + aoff1 + k1, As0 + 2048 + t*8);
      gl2lds(A1 + aoff0 + k1, As1 + t*8);
      gl2lds(A1 + aoff1 + k1, As1 + 2048 + t*8);
      gl2lds(B0 + boff0 + k1, Bs0 + t*8);
      gl2lds(B0 + boff1 + k1, Bs0 + 2048 + t*8);
      gl2lds(B1 + boff0 + k1, Bs1 + t*8);
      gl2lds(B1 + boff1 + k1, Bs1 + 2048 + t*8);
    }
    #pragma unroll
    for (int i=0;i<4;i++)
      #pragma unroll
      for (int j=0;j<4;j++){
        acc[i][j] = mfma16(a0[i], b0[j], acc[i][j]);
        acc[i][j] = mfma16(a0[i], b1[j], acc[i][j]);
        acc[i][j] = mfma16(a1[i], b0[j], acc[i][j]);
      }
  }
}

// fused 3x3 split k-loop (6 combos: hh, hm, mh, hl, mm, lh); 2-phase prefetch.
__device__ __forceinline__ void kloop3(const bf16* __restrict__ A0, const bf16* __restrict__ A1,
                                       const bf16* __restrict__ A2, int lda, int m0,
                                       const bf16* __restrict__ B0, const bf16* __restrict__ B1,
                                       const bf16* __restrict__ B2, int ldb, int n0, int K,
                                       bf16* As0, bf16* As1, bf16* As2,
                                       bf16* Bs0, bf16* Bs1, bf16* Bs2,
                                       f32x4 acc[4][4]){
  const int t = threadIdx.x;
  const int r = t>>2;
  const int sw = (t&3) ^ ((t>>3)&3);
  const long aoff0 = (long)(m0 + r)*lda + sw*8;
  const long aoff1 = (long)(m0 + 64 + r)*lda + sw*8;
  const long boff0 = (long)(n0 + r)*ldb + sw*8;
  const long boff1 = boff0 + (long)64*ldb;
  const int wave = t>>6, lane = t&63;
  const int qr = wave>>1, qc = wave&1, ln = lane&15, kq = lane>>4;
  const int slot = kq ^ ((ln>>1)&3);
  const int ao = (qr*64 + ln)*32 + slot*8;
  const int bo = (qc*64 + ln)*32 + slot*8;
  // prologue: stage k0 = 0
  gl2lds(A0 + aoff0, As0 + t*8);
  gl2lds(A0 + aoff1, As0 + 2048 + t*8);
  gl2lds(A1 + aoff0, As1 + t*8);
  gl2lds(A1 + aoff1, As1 + 2048 + t*8);
  gl2lds(A2 + aoff0, As2 + t*8);
  gl2lds(A2 + aoff1, As2 + 2048 + t*8);
  gl2lds(B0 + boff0, Bs0 + t*8);
  gl2lds(B0 + boff1, Bs0 + 2048 + t*8);
  gl2lds(B1 + boff0, Bs1 + t*8);
  gl2lds(B1 + boff1, Bs1 + 2048 + t*8);
  gl2lds(B2 + boff0, Bs2 + t*8);
  gl2lds(B2 + boff1, Bs2 + 2048 + t*8);
  for (int k0 = 0; k0 < K; k0 += 32){
    __syncthreads();
    short8 a0[4], a1[4], a2[4], b0[4], b1[4], b2[4];
    #pragma unroll
    for (int i=0;i<4;i++){
      a0[i] = *(const short8*)(As0 + ao + i*512);
      a1[i] = *(const short8*)(As1 + ao + i*512);
      a2[i] = *(const short8*)(As2 + ao + i*512);
    }
    #pragma unroll
    for (int j=0;j<4;j++){
      b0[j] = *(const short8*)(Bs0 + bo + j*512);
      b1[j] = *(const short8*)(Bs1 + bo + j*512);
      b2[j] = *(const short8*)(Bs2 + bo + j*512);
    }
    __syncthreads();
    int k1 = k0 + 32;
    if (k1 < K){
      gl2lds(A0 + aoff0 + k1, As0 + t*8);
      gl2lds(A0 + aoff1 + k1, As0 + 2048 + t*8);
      gl2lds(A1 + aoff0 + k1, As1 + t*8);
      gl2lds(A1 + aoff1 + k1, As1 + 2048 + t*8);
      gl2lds(A2 + aoff0 + k1, As2 + t*8);
      gl2lds(A2 + aoff1 + k1, As2 + 2048 + t*8);
      gl2lds(B0 + boff0 + k1, Bs0 + t*8);
      gl2lds(B0 + boff1 + k1, Bs0 + 2048 + t*8);
      gl2lds(B1 + boff0 + k1, Bs1 + t*8);
      gl2lds(B1 + boff1 + k1, Bs1 + 2048 + t*8);
      gl2lds(B2 + boff0 + k1, Bs2 + t*8);
      gl2lds(B2 + boff1 + k1, Bs2 + 2048 + t*8);
    }
    #pragma unroll
    for (int i=0;i<4;i++)
      #pragma unroll
      for (int j=0;j<4;j++){
        acc[i][j] = mfma16(a0[i], b0[j], acc[i][j]);
        acc[i][j] = mfma16(a0[i], b1[j], acc[i][j]);
        acc[i][j] = mfma16(a1[i], b0[j], acc[i][j]);
        acc[i][j] = mfma16(a0[i], b2[j], acc[i][j]);
        acc[i][j] = mfma16(a1[i], b1[j], acc[i][j]);
        acc[i][j] = mfma16(a2[i], b0[j], acc[i][j]);
      }
  }
}

#define EPI_SETUP \
  const int t = threadIdx.x, wave=t>>6, lane=t&63; \
  const int qr=wave>>1, qc=wave&1, ln=lane&15, kq=lane>>4; (void)qr;

#define ACC_INIT \
  f32x4 acc[4][4]; \
  _Pragma("unroll") for (int i=0;i<4;i++) _Pragma("unroll") for (int j=0;j<4;j++) \
    acc[i][j] = (f32x4){0.f,0.f,0.f,0.f};

// ================= fused prep (one launch) =================
__device__ __forceinline__ void split3_body(const float* __restrict__ in,
    bf16* __restrict__ oh, bf16* __restrict__ om, bf16* __restrict__ ol, int b, int n4){
  int i = b*256 + threadIdx.x;
  if (i >= n4) return;
  float4 v = ((const float4*)in)[i];
  float vv[4] = {v.x, v.y, v.z, v.w};
  u16 hs[4], ms[4], ls[4];
  #pragma unroll
  for (int c=0;c<4;c++){
    bf16 h = __float2bfloat16(vv[c]); float r1 = vv[c] - __bfloat162float(h);
    bf16 m = __float2bfloat16(r1);    float r2 = r1 - __bfloat162float(m);
    bf16 l = __float2bfloat16(r2);
    hs[c]=*(u16*)&h; ms[c]=*(u16*)&m; ls[c]=*(u16*)&l;
  }
  ((ushort4*)oh)[i] = (ushort4){hs[0],hs[1],hs[2],hs[3]};
  ((ushort4*)om)[i] = (ushort4){ms[0],ms[1],ms[2],ms[3]};
  ((ushort4*)ol)[i] = (ushort4){ls[0],ls[1],ls[2],ls[3]};
}

__device__ __forceinline__ void tsplit3_body(const float* __restrict__ in,
    bf16* __restrict__ oh, bf16* __restrict__ om, bf16* __restrict__ ol,
    int R, int C, int bx, int by, float* tile /*[64][65]*/){
  int r0 = by*64, c0 = bx*64;
  int t = threadIdx.x, lr = t>>4, lc = (t&15)*4;
  #pragma unroll
  for (int it=0; it<4; it++){
    int rr = it*16 + lr;
    float4 v = *(const float4*)(in + (long)(r0+rr)*C + c0 + lc);
    tile[rr*65+lc]=v.x; tile[rr*65+lc+1]=v.y; tile[rr*65+lc+2]=v.z; tile[rr*65+lc+3]=v.w;
  }
  __syncthreads();
  #pragma unroll
  for (int it=0; it<4; it++){
    int cc = it*16 + lr;
    u16 hs[4], ms[4], ls[4];
    #pragma unroll
    for (int j=0;j<4;j++){
      float v = tile[(lc+j)*65+cc];
      bf16 h = __float2bfloat16(v); float r1 = v - __bfloat162float(h);
      bf16 m = __float2bfloat16(r1); float r2 = r1 - __bfloat162float(m);
      bf16 l = __float2bfloat16(r2);
      hs[j]=*(u16*)&h; ms[j]=*(u16*)&m; ls[j]=*(u16*)&l;
    }
    long oi = (long)(c0+cc)*R + r0 + lc;
    *(ushort4*)((u16*)oh + oi) = (ushort4){hs[0],hs[1],hs[2],hs[3]};
    *(ushort4*)((u16*)om + oi) = (ushort4){ms[0],ms[1],ms[2],ms[3]};
    *(ushort4*)((u16*)ol + oi) = (ushort4){ls[0],ls[1],ls[2],ls[3]};
  }
}

__device__ __forceinline__ void cvtT_body(const float* __restrict__ in,
    bf16* __restrict__ out, int R, int C, int bx, int by, int bz, float* tile){
  long zb = (long)bz * R * C;
  int r0 = by*64, c0 = bx*64;
  int t = threadIdx.x, lr = t>>4, lc = (t&15)*4;
  #pragma unroll
  for (int it=0; it<4; it++){
    int rr = it*16 + lr;
    float4 v = *(const float4*)(in + zb + (long)(r0+rr)*C + c0 + lc);
    tile[rr*65+lc]=v.x; tile[rr*65+lc+1]=v.y; tile[rr*65+lc+2]=v.z; tile[rr*65+lc+3]=v.w;
  }
  __syncthreads();
  #pragma unroll
  for (int it=0; it<4; it++){
    int cc = it*16 + lr;
    u16 hs[4];
    #pragma unroll
    for (int j=0;j<4;j++){
      bf16 h = __float2bfloat16(tile[(lc+j)*65+cc]);
      hs[j]=*(u16*)&h;
    }
    *(ushort4*)((u16*)out + zb + (long)(c0+cc)*R + r0 + lc) = (ushort4){hs[0],hs[1],hs[2],hs[3]};
  }
}

__device__ __forceinline__ void cvec_body(const float* __restrict__ bmap,
    const float* __restrict__ Wr, const float* __restrict__ br, float* __restrict__ cvec, int b){
  int id = b*256 + threadIdx.x;   // (e,j)
  int e = id >> 9, j = id & 511;
  float s = 0.f;
  for (int k=0;k<512;k++) s += bmap[e*512+k] * Wr[k*512 + j];
  cvec[id] = s + br[j];
}

__global__ __launch_bounds__(256) void k_prep(const float* __restrict__ x,
    const float* __restrict__ Wmap, const float* __restrict__ Wr,
    const float* __restrict__ bmap, const float* __restrict__ br,
    const float* __restrict__ W1, const float* __restrict__ W2,
    const float* __restrict__ W3, const float* __restrict__ Wo,
    bf16* xh, bf16* xm, bf16* xl,
    bf16* Wm_h, bf16* Wm_m, bf16* Wm_l,
    bf16* WrT_h, bf16* WrT_m, bf16* WrT_l, float* cvec,
    bf16* W1T, bf16* W2T, bf16* W3T, bf16* WoT){
  __shared__ float tile[64*65];
  int b = blockIdx.x;
  if (b < 2048){ split3_body(x, xh, xm, xl, b, 524288); return; }
  b -= 2048;
  if (b < 2048){ split3_body(Wmap, Wm_h, Wm_m, Wm_l, b, 524288); return; }
  b -= 2048;
  if (b < 64){ tsplit3_body(Wr, WrT_h, WrT_m, WrT_l, 512, 512, b&7, b>>3, tile); return; }
  b -= 64;
  if (b < 16){ cvec_body(bmap, Wr, br, cvec, b); return; }
  b -= 16;
  if (b < 1024){ cvtT_body(W1, W1T, 512, 1024, b&15, (b>>4)&7, b>>7, tile); return; }
  b -= 1024;
  if (b < 2048){ cvtT_body(W2, W2T, 1024, 1024, b&15, (b>>4)&15, b>>8, tile); return; }
  b -= 2048;
  if (b < 2048){ cvtT_body(W3, W3T, 1024, 1024, b&15, (b>>4)&15, b>>8, tile); return; }
  b -= 2048;
  cvtT_body(Wo, WoT, 1024, 512, b&7, b>>3, 0, tile);
}
#define PREP_BLOCKS 9424

// ---- MT_e[j,d] = sum_k Wr[k,j] * Wmap[d, e*512+k] — fused 6-combo single k-loop
__global__ __launch_bounds__(256) void k_gemm_MT(
    const bf16* __restrict__ Rh, const bf16* __restrict__ Rm, const bf16* __restrict__ Rl,
    const bf16* __restrict__ Wh, const bf16* __restrict__ Wm, const bf16* __restrict__ Wl,
    bf16* __restrict__ MTh, bf16* __restrict__ MTm, float* __restrict__ M32){
  __shared__ __align__(16) bf16 As0[4096], As1[4096], As2[4096],
                                Bs0[4096], Bs1[4096], Bs2[4096];
  int m0 = blockIdx.x*128, n0 = blockIdx.y*128, e = blockIdx.z;
  ACC_INIT
  kloop3(Rh, Rm, Rl, 512, m0, Wh + e*512, Wm + e*512, Wl + e*512, DE, n0, 512,
         As0, As1, As2, Bs0, Bs1, Bs2, acc);
  EPI_SETUP
  int cg[4];
  #pragma unroll
  for (int j=0;j<4;j++) cg[j] = n0 + qc*64 + j*16 + ln;
  long eb = (long)e*512*512;
  #pragma unroll
  for (int i=0;i<4;i++)
    #pragma unroll
    for (int r=0;r<4;r++){
      long base = eb + (long)(m0 + qr*64 + i*16 + kq*4 + r) * 512;
      #pragma unroll
      for (int j=0;j<4;j++){
        float v = acc[i][j][r];
        bf16 h = __float2bfloat16(v); float r1 = v - __bfloat162float(h);
        bf16 m = __float2bfloat16(r1);
        MTh[base + cg[j]] = h; MTm[base + cg[j]] = m; M32[base + cg[j]] = v;
      }
    }
}

// ---- re = x @ MT_e^T + c_e — fused 3-combo (hh+hm+mh) single k-loop;
// epilogue: dist2[n,e] += (x-re)^2 in fp64
__global__ __launch_bounds__(256) void k_gemm_re(
    const bf16* __restrict__ xh, const bf16* __restrict__ xm,
    const bf16* __restrict__ MTh, const bf16* __restrict__ MTm,
    const float* __restrict__ cvec, const float* __restrict__ x, double* __restrict__ dist2){
  __shared__ __align__(16) bf16 As0[4096], As1[4096], Bs0[4096], Bs1[4096];
  int m0 = blockIdx.x*128, n0 = blockIdx.y*128, e = blockIdx.z;
  ACC_INIT
  long eb = (long)e*512*512;
  kloop2(xh, xm, 512, m0, MTh + eb, MTm + eb, 512, n0, 512,
         As0, As1, Bs0, Bs1, acc);
  EPI_SETUP
  int cg[4]; float cv[4];
  #pragma unroll
  for (int j=0;j<4;j++){ cg[j] = n0 + qc*64 + j*16 + ln; cv[j] = cvec[e*512 + cg[j]]; }
  #pragma unroll
  for (int i=0;i<4;i++)
    #pragma unroll
    for (int r=0;r<4;r++){
      int rg = m0 + qr*64 + i*16 + kq*4 + r;      // token index
      const float* xr = x + (long)rg*512;
      double s = 0.0;
      #pragma unroll
      for (int j=0;j<4;j++){
        float re = acc[i][j][r] + cv[j];
        float d  = xr[cg[j]] - re;
        s += (double)d * (double)d;
      }
      s += __shfl_xor(s,1); s += __shfl_xor(s,2); s += __shfl_xor(s,4); s += __shfl_xor(s,8);
      if (ln == 0) atomicAdd(&dist2[(long)rg*EE + e], s);
    }
}

// ---- expert GEMM (ragged tile table, optional gather), gelu epilogue, fp32 bias
__global__ __launch_bounds__(256) void k_gemm_exp(const Tile* __restrict__ table,
    const bf16* __restrict__ A, int lda, const int* __restrict__ rowmap,
    const bf16* __restrict__ Wt, long wstride, int ldb, int K,
    const float* __restrict__ bias, int ncols, bf16* __restrict__ out, int ldo){
  Tile tc = table[blockIdx.x];
  if (tc.e < 0) return;
  __shared__ __align__(16) bf16 As[4096], Bs[4096];
  int n0 = blockIdx.y*128;
  ACC_INIT
  const bf16* BT = Wt + (long)tc.e*wstride;
  if (rowmap) kloop<true >(A, lda, rowmap, tc.row0, BT, ldb, n0, K, As, Bs, acc);
  else        kloop<false>(A, lda, nullptr, tc.row0, BT, ldb, n0, K, As, Bs, acc);
  EPI_SETUP
  const float* bp = bias + (long)tc.e*ncols;
  int cg[4]; float bv[4];
  #pragma unroll
  for (int j=0;j<4;j++){ cg[j] = n0 + qc*64 + j*16 + ln; bv[j] = bp[cg[j]]; }
  #pragma unroll
  for (int i=0;i<4;i++)
    #pragma unroll
    for (int r=0;r<4;r++){
      int rl = qr*64 + i*16 + kq*4 + r;
      if (rl < tc.rows){
        bf16* op = out + (long)(tc.row0 + rl)*ldo;
        #pragma unroll
        for (int j=0;j<4;j++)
          op[cg[j]] = __float2bfloat16(gelu_f(acc[i][j][r] + bv[j]));
      }
    }
}

// ---- out-proj GEMM: obuf = gelu(comb @ Wo + bo)
__global__ __launch_bounds__(256) void k_gemm_go(const bf16* __restrict__ A,
    const bf16* __restrict__ WoT, const float* __restrict__ bias, bf16* __restrict__ out){
  __shared__ __align__(16) bf16 As[4096], Bs[4096];
  int m0 = blockIdx.x*128, n0 = blockIdx.y*128;
  ACC_INIT
  kloop<false>(A, HH, nullptr, m0, WoT, HH, n0, HH, As, Bs, acc);
  EPI_SETUP
  int cg[4]; float bv[4];
  #pragma unroll
  for (int j=0;j<4;j++){ cg[j] = n0 + qc*64 + j*16 + ln; bv[j] = bias[cg[j]]; }
  #pragma unroll
  for (int i=0;i<4;i++)
    #pragma unroll
    for (int r=0;r<4;r++){
      long base = (long)(m0 + qr*64 + i*16 + kq*4 + r) * OUTD;
      #pragma unroll
      for (int j=0;j<4;j++)
        out[base + cg[j]] = __float2bfloat16(gelu_f(acc[i][j][r] + bv[j]));
    }
}

// ---- router select (fp64): top-2 LARGEST dist; flags low-margin tokens for rescue
__global__ __launch_bounds__(256) void k_select(const double* __restrict__ dist2,
    float* __restrict__ selp, int* __restrict__ seli, int* __restrict__ counts,
    float* __restrict__ entacc, int* __restrict__ flaglist, int* __restrict__ nflag){
  __shared__ int hc[EE];
  int t = threadIdx.x;
  if (t < EE) hc[t] = 0;
  __syncthreads();
  int n = blockIdx.x*256 + t;
  double d0 = -1.0, d1 = -1.0, d2 = -1.0; int i0 = 0, i1 = 0;
  #pragma unroll
  for (int e=0;e<EE;e++){
    double d = sqrt(dist2[(long)n*EE + e]);
    if (d > d0){ d2 = d1; d1 = d0; i1 = i0; d0 = d; i0 = e; }
    else if (d > d1){ d2 = d1; d1 = d; i1 = e; }
    else if (d > d2){ d2 = d; }
  }
  if (d1 - d2 < DMARGIN){ int p = atomicAdd(nflag, 1); flaglist[p & (FCAP-1)] = n; }
  double s0 = exp(-d0), s1 = exp(-d1);   // s0 = smallest sim -> slot 0
  double den = s0 + s1;
  float p0 = (float)(s0/den), p1 = (float)(s1/den);
  selp[2*n] = p0; selp[2*n+1] = p1;
  seli[2*n] = i0; seli[2*n+1] = i1;
  atomicAdd(&hc[i0], 1); atomicAdd(&hc[i1], 1);
  float a0 = p0, a1 = p1;
  float a2 = p0*logf(p0+1e-6f) + p1*logf(p1+1e-6f);
  #pragma unroll
  for (int m=32;m;m>>=1){ a0 += __shfl_down(a0,m); a1 += __shfl_down(a1,m); a2 += __shfl_down(a2,m); }
  if ((t&63)==0){ atomicAdd(&entacc[0], a0); atomicAdd(&entacc[1], a1); atomicAdd(&entacc[2], a2); }
  __syncthreads();
  if (t < EE) atomicAdd(&counts[t], hc[t]);
}

// ---- rescue: one (flagged-token, expert, j-chunk) work item per block iteration.
// Each pair is split over RSPLIT=4 blocks (128 rows each); each wave handles 32
// rows, batched 8 rows per shuffle-reduce round so 16 float4 loads are in flight
// at once. Partial sums land in rbuf4[pid*RSPLIT + chunk]; k_scan sums the chunks.
__global__ __launch_bounds__(256) void k_rescue(const int* __restrict__ flaglist,
    const int* __restrict__ nflag, const float* __restrict__ x,
    const float* __restrict__ M32, const float* __restrict__ cvec,
    double* __restrict__ rbuf4){
  __shared__ float xs[512];
  __shared__ double wsum[4];
  int t = threadIdx.x, w = t>>6, l = t&63;
  int nf = *nflag; if (nf > FCAP) nf = FCAP;
  int work = nf * EE * RSPLIT;
  for (int wid = blockIdx.x; wid < work; wid += gridDim.x){
    int pid = wid >> 2, chunk = wid & (RSPLIT-1);
    int f = pid >> 3, e = pid & 7;
    int n = flaglist[f];
    xs[t] = x[(long)n*512 + t]; xs[t+256] = x[(long)n*512 + 256 + t];
    __syncthreads();
    const float* Me = M32 + ((long)e << 18);
    const float* xp = xs + l*8;
    float x0=xp[0], x1=xp[1], x2=xp[2], x3=xp[3], x4=xp[4], x5=xp[5], x6=xp[6], x7=xp[7];
    double s = 0.0;
    int j0 = chunk*128 + w*32;
    for (int rb = 0; rb < 32; rb += 8){
      double d[8];
      #pragma unroll
      for (int rr=0; rr<8; rr++){
        const float* Mr = Me + (long)(j0 + rb + rr)*512 + l*8;
        float4 a = *(const float4*)Mr, b = *(const float4*)(Mr+4);
        d[rr] = (double)a.x*x0 + (double)a.y*x1 + (double)a.z*x2 + (double)a.w*x3
              + (double)b.x*x4 + (double)b.y*x5 + (double)b.z*x6 + (double)b.w*x7;
      }
      #pragma unroll
      for (int m=32;m;m>>=1){
        #pragma unroll
        for (int rr=0; rr<8; rr++) d[rr] += __shfl_down(d[rr], m);
      }
      if (l == 0){
        #pragma unroll
        for (int rr=0; rr<8; rr++){
          int j = j0 + rb + rr;
          double diff = (double)xs[j] - (d[rr] + (double)cvec[e*512 + j]);
          s += diff*diff;
        }
      }
    }
    if (l == 0) wsum[w] = s;
    __syncthreads();
    if (t == 0) rbuf4[wid] = wsum[0]+wsum[1]+wsum[2]+wsum[3];
    __syncthreads();
  }
}

// ---- merged: rescue patch (parallel) + tile-table scan (thread 0)
__global__ __launch_bounds__(256) void k_scan(const int* __restrict__ flaglist,
    const int* __restrict__ nflag, const double* __restrict__ rbuf4,
    float* __restrict__ selp, int* __restrict__ seli,
    int* __restrict__ counts, float* __restrict__ entacc,
    int* __restrict__ cursors, Tile* __restrict__ table, float* __restrict__ entout){
  int t = threadIdx.x;
  int nf = *nflag; if (nf > FCAP) nf = FCAP;
  for (int idx = t; idx < nf; idx += 256){
    int n = flaglist[idx];
    double d0=-1.0, d1=-1.0; int i0=0, i1=0;
    #pragma unroll
    for (int e=0;e<EE;e++){
      const double* rp = rbuf4 + ((long)(idx*EE + e))*RSPLIT;
      double d = sqrt(rp[0] + rp[1] + rp[2] + rp[3]);
      if (d > d0){ d1=d0; i1=i0; d0=d; i0=e; }
      else if (d > d1){ d1=d; i1=e; }
    }
    double s0 = exp(-d0), s1 = exp(-d1), den = s0+s1;
    float p0 = (float)(s0/den), p1 = (float)(s1/den);
    int o0 = seli[2*n], o1 = seli[2*n+1];
    float q0 = selp[2*n], q1 = selp[2*n+1];
    if (o0 != i0 || o1 != i1){
      atomicSub(&counts[o0], 1); atomicSub(&counts[o1], 1);
      atomicAdd(&counts[i0], 1); atomicAdd(&counts[i1], 1);
      seli[2*n] = i0; seli[2*n+1] = i1;
    }
    atomicAdd(&entacc[0], p0 - q0);
    atomicAdd(&entacc[1], p1 - q1);
    atomicAdd(&entacc[2], (p0*logf(p0+1e-6f) + p1*logf(p1+1e-6f))
                        - (q0*logf(q0+1e-6f) + q1*logf(q1+1e-6f)));
    selp[2*n] = p0; selp[2*n+1] = p1;
  }
  __threadfence();
  __syncthreads();
  if (t != 0) return;
  int off = 0, ti = 0;
  for (int e=0;e<EE;e++){
    cursors[e] = off;
    int c = counts[e];
    for (int r=0;r<c;r+=128){
      table[ti].e = e; table[ti].row0 = off + r;
      table[ti].rows = (c - r < 128) ? (c - r) : 128; ti++;
    }
    off += c;
  }
  for (; ti<MAXT; ti++){ table[ti].e = -1; table[ti].row0 = 0; table[ti].rows = 0; }
  float pm0 = entacc[0] * (1.0f/NTOK), pm1 = entacc[1] * (1.0f/NTOK);
  *entout = pm0*logf(pm0 + 1e-6f) + pm1*logf(pm1 + 1e-6f) - entacc[2] * (1.0f/NTOK);
}

__global__ __launch_bounds__(256) void k_place(const int* __restrict__ seli,
    const float* __restrict__ selp, int* __restrict__ cursors,
    int* __restrict__ atok, float* __restrict__ ap, int* __restrict__ aslot,
    int* __restrict__ aexp){
  int id = blockIdx.x*256 + threadIdx.x;   // 8192 = (token, slot)
  int e = seli[id];
  int pos = atomicAdd(&cursors[e], 1);
  atok[pos] = id >> 1;
  ap[pos]   = selp[id];
  aslot[pos]= id & 1;
  aexp[pos] = e;
}

__device__ __forceinline__ void blkred2(float& s, float& q, int t){
  #pragma unroll
  for (int m=32;m;m>>=1){ s += __shfl_down(s,m); q += __shfl_down(q,m); }
  __shared__ float shs[4], shq[4];
  if ((t&63)==0){ shs[t>>6] = s; shq[t>>6] = q; }
  __syncthreads();
  s = shs[0]+shs[1]+shs[2]+shs[3];
  q = shq[0]+shq[1]+shq[2]+shq[3];
}

// ---- LayerNorm over H=1024 per assignment row, per-expert fp32 gamma/beta
__global__ __launch_bounds__(256) void k_ln_mid(const bf16* __restrict__ in, bf16* __restrict__ out,
    const float* __restrict__ g, const float* __restrict__ be, const int* __restrict__ aexp){
  int row = blockIdx.x, t = threadIdx.x;
  const ushort4 u = *(const ushort4*)((const u16*)in + (long)row*HH + t*4);
  float v0=b2f(u.x), v1=b2f(u.y), v2=b2f(u.z), v3=b2f(u.w);
  float s = v0+v1+v2+v3;
  float q = v0*v0+v1*v1+v2*v2+v3*v3;
  blkred2(s, q, t);
  float mu = s*(1.0f/HH);
  float rs = rsqrtf(q*(1.0f/HH) - mu*mu + 1e-5f);
  int e = aexp[row];
  const float4 ug = *(const float4*)(g  + (long)e*HH + t*4);
  const float4 ub = *(const float4*)(be + (long)e*HH + t*4);
  bf16* op = out + (long)row*HH + t*4;
  op[0] = __float2bfloat16((v0-mu)*rs*ug.x + ub.x);
  op[1] = __float2bfloat16((v1-mu)*rs*ug.y + ub.y);
  op[2] = __float2bfloat16((v2-mu)*rs*ug.z + ub.z);
  op[3] = __float2bfloat16((v3-mu)*rs*ug.w + ub.w);
}

// ---- LN3 + gate multiply + scatter to per-slot fp32 buffer
__global__ __launch_bounds__(256) void k_ln3(const bf16* __restrict__ in, float* __restrict__ slots,
    const float* __restrict__ g, const float* __restrict__ be, const int* __restrict__ aexp,
    const int* __restrict__ atok, const int* __restrict__ aslot, const float* __restrict__ ap){
  int row = blockIdx.x, t = threadIdx.x;
  const ushort4 u = *(const ushort4*)((const u16*)in + (long)row*HH + t*4);
  float v0=b2f(u.x), v1=b2f(u.y), v2=b2f(u.z), v3=b2f(u.w);
  float s = v0+v1+v2+v3;
  float q = v0*v0+v1*v1+v2*v2+v3*v3;
  blkred2(s, q, t);
  float mu = s*(1.0f/HH);
  float rs = rsqrtf(q*(1.0f/HH) - mu*mu + 1e-5f);
  int e = aexp[row];
  const float4 ug = *(const float4*)(g  + (long)e*HH + t*4);
  const float4 ub = *(const float4*)(be + (long)e*HH + t*4);
  float p = ap[row];
  float* op = slots + ((long)atok[row]*2 + aslot[row])*HH + t*4;
  op[0] = p*((v0-mu)*rs*ug.x + ub.x);
  op[1] = p*((v1-mu)*rs*ug.y + ub.y);
  op[2] = p*((v2-mu)*rs*ug.z + ub.z);
  op[3] = p*((v3-mu)*rs*ug.w + ub.w);
}

__global__ __launch_bounds__(256) void k_comb(const float* __restrict__ slots, bf16* __restrict__ comb){
  long i = (long)blockIdx.x*256 + threadIdx.x;
  long n = i >> 10, c = i & 1023;
  comb[i] = __float2bfloat16(slots[n*2*HH + c] + slots[(n*2+1)*HH + c]);
}

// ---- final LN over OUT=512 -> d_out (fp32); also writes ent_loss
__global__ __launch_bounds__(256) void k_lnout(const bf16* __restrict__ in, float* __restrict__ dout,
    const float* __restrict__ g, const float* __restrict__ be, const float* __restrict__ entout){
  int row = blockIdx.x, t = threadIdx.x;
  const bf16* ip = in + (long)row*OUTD + t*2;
  float v0 = __bfloat162float(ip[0]), v1 = __bfloat162float(ip[1]);
  float s = v0+v1, q = v0*v0+v1*v1;
  blkred2(s, q, t);
  float mu = s*(1.0f/OUTD);
  float rs = rsqrtf(q*(1.0f/OUTD) - mu*mu + 1e-5f);
  float g0 = g[t*2], g1v = g[t*2+1];
  float b0 = be[t*2], b1v = be[t*2+1];
  float* op = dout + (long)row*OUTD + t*2;
  op[0] = (v0-mu)*rs*g0 + b0;
  op[1] = (v1-mu)*rs*g1v + b1v;
  if (row==0 && t==0) dout[(long)NTOK*OUTD] = *entout;
}

extern "C" void kernel_launch(void* const* d_in, const int* in_sizes, int n_in,
                              void* d_out, int out_size, void* d_ws, size_t ws_size,
                              hipStream_t stream){
  (void)in_sizes; (void)n_in; (void)out_size; (void)ws_size;
  const float* x    = (const float*)d_in[0];
  const float* Wmap = (const float*)d_in[1];
  const float* bmap = (const float*)d_in[2];
  const float* Wr   = (const float*)d_in[3];
  const float* br   = (const float*)d_in[4];
  const float* W1   = (const float*)d_in[5];
  const float* b1   = (const float*)d_in[6];
  const float* g1   = (const float*)d_in[7];
  const float* be1  = (const float*)d_in[8];
  const float* W2   = (const float*)d_in[9];
  const float* b2   = (const float*)d_in[10];
  const float* g2   = (const float*)d_in[11];
  const float* be2  = (const float*)d_in[12];
  const float* W3   = (const float*)d_in[13];
  const float* b3   = (const float*)d_in[14];
  const float* g3   = (const float*)d_in[15];
  const float* be3  = (const float*)d_in[16];
  const float* Wo   = (const float*)d_in[17];
  const float* bo   = (const float*)d_in[18];
  const float* go   = (const float*)d_in[19];
  const float* beo  = (const float*)d_in[20];

  char* ws = (char*)d_ws;
  size_t o = 0;
  auto take = [&](size_t b){ size_t r = o; o += (b + 255) & ~(size_t)255; return r; };
  size_t o_xh   = take((size_t)NTOK*DD*2);     // bf16(x); also expert-GEMM1 A
  size_t o_xm   = take((size_t)NTOK*DD*2);     // comb overlays xm+xl
  size_t o_xl   = take((size_t)NTOK*DD*2);
  size_t o_R1   = take((size_t)APAD*HH*2);     // phase1: Wmap splits + WrT splits + cvec; phase2: hba
  size_t o_R2   = take((size_t)APAD*HH*2);     // phase1: MTh+MTm+M32;                    phase2: hbb
  size_t o_W1T  = take((size_t)EE*HH*DD*2);    // obuf overlays front half
  size_t o_W2T  = take((size_t)EE*HH*HH*2);    // slots overlays W2T+W3T (exactly 32 MB)
  size_t o_W3T  = take((size_t)EE*HH*HH*2);
  size_t o_WoT  = take((size_t)OUTD*HH*2);
  size_t o_dist2= take((size_t)NTOK*EE*8);     // zeroed (fp64)
  size_t o_cnt  = take(64);                    // zeroed
  size_t o_ent  = take(64);                    // zeroed
  size_t o_nfl  = take(64);                    // zeroed
  size_t o_cur  = take(64);
  size_t o_eout = take(64);
  size_t o_flag = take((size_t)FCAP*4);
  size_t o_rbuf = take((size_t)FCAP*EE*RSPLIT*8);
  size_t o_selp = take((size_t)NTOK*2*4);
  size_t o_seli = take((size_t)NTOK*2*4);
  size_t o_atok = take((size_t)ATOT*4);
  size_t o_ap   = take((size_t)ATOT*4);
  size_t o_aslt = take((size_t)ATOT*4);
  size_t o_aexp = take((size_t)ATOT*4);
  size_t o_tab  = take((size_t)MAXT*sizeof(Tile));

  bf16* xh=(bf16*)(ws+o_xh); bf16* xm=(bf16*)(ws+o_xm); bf16* xl=(bf16*)(ws+o_xl);
  // R1 sub-layout (phase 1)
  bf16* Wm_h=(bf16*)(ws+o_R1);
  bf16* Wm_m=(bf16*)(ws+o_R1+ 4194304);
  bf16* Wm_l=(bf16*)(ws+o_R1+ 8388608);
  bf16* WrT_h=(bf16*)(ws+o_R1+12582912);
  bf16* WrT_m=(bf16*)(ws+o_R1+13107200);
  bf16* WrT_l=(bf16*)(ws+o_R1+13631488);
  float* cvec=(float*)(ws+o_R1+14155776);
  // R2 sub-layout (phase 1): MTh (4MB) + MTm (4MB) + M32 fp32 (8MB) = 16MB <= 17MB
  bf16* MT_h=(bf16*)(ws+o_R2);
  bf16* MT_m=(bf16*)(ws+o_R2+4194304);
  float* M32=(float*)(ws+o_R2+8388608);
  // phase-2 overlays
  bf16* hba=(bf16*)(ws+o_R1);
  bf16* hbb=(bf16*)(ws+o_R2);
  bf16* W1T=(bf16*)(ws+o_W1T); bf16* W2T=(bf16*)(ws+o_W2T); bf16* W3T=(bf16*)(ws+o_W3T);
  bf16* WoT=(bf16*)(ws+o_WoT);
  float* slots=(float*)(ws+o_W2T);             // 32 MB = W2T+W3T
  bf16* comb=(bf16*)(ws+o_xm);                 // 8 MB = xm+xl
  bf16* obuf=(bf16*)(ws+o_W1T);                // 4 MB of W1T
  double* dist2=(double*)(ws+o_dist2);
  int* counts=(int*)(ws+o_cnt); float* entacc=(float*)(ws+o_ent);
  int* nflag=(int*)(ws+o_nfl);
  int* cursors=(int*)(ws+o_cur); float* entout=(float*)(ws+o_eout);
  int* flaglist=(int*)(ws+o_flag);
  double* rbuf4=(double*)(ws+o_rbuf);
  float* selp=(float*)(ws+o_selp); int* seli=(int*)(ws+o_seli);
  int* atok=(int*)(ws+o_atok); float* ap=(float*)(ws+o_ap);
  int* aslot=(int*)(ws+o_aslt); int* aexp=(int*)(ws+o_aexp);
  Tile* table=(Tile*)(ws+o_tab);

  hipMemsetAsync(ws + o_dist2, 0, (o_nfl + 64) - o_dist2, stream);

  // fused convert / split / transpose (one launch)
  k_prep<<<PREP_BLOCKS,256,0,stream>>>(x, Wmap, Wr, bmap, br, W1, W2, W3, Wo,
      xh, xm, xl, Wm_h, Wm_m, Wm_l, WrT_h, WrT_m, WrT_l, cvec, W1T, W2T, W3T, WoT);

  // router
  k_gemm_MT<<<dim3(4,4,8),256,0,stream>>>(WrT_h, WrT_m, WrT_l, Wm_h, Wm_m, Wm_l,
                                          MT_h, MT_m, M32);
  k_gemm_re<<<dim3(32,4,8),256,0,stream>>>(xh, xm, MT_h, MT_m, cvec, x, dist2);
  k_select<<<16,256,0,stream>>>(dist2, selp, seli, counts, entacc, flaglist, nflag);
  k_rescue<<<2048,256,0,stream>>>(flaglist, nflag, x, M32, cvec, rbuf4);
  k_scan<<<1,256,0,stream>>>(flaglist, nflag, rbuf4, selp, seli, counts, entacc,
                             cursors, table, entout);
  k_place<<<32,256,0,stream>>>(seli, selp, cursors, atok, ap, aslot, aexp);

  // expert MLP (sparse, N*K = 8192 rows)
  k_gemm_exp<<<dim3(MAXT,8),256,0,stream>>>(table, xh, DD, atok,
      W1T, (long)HH*DD, DD, DD, b1, HH, hba, HH);
  k_ln_mid<<<ATOT,256,0,stream>>>(hba, hbb, g1, be1, aexp);
  k_gemm_exp<<<dim3(MAXT,8),256,0,stream>>>(table, hbb, HH, nullptr,
      W2T, (long)HH*HH, HH, HH, b2, HH, hba, HH);
  k_ln_mid<<<ATOT,256,0,stream>>>(hba, hbb, g2, be2, aexp);
  k_gemm_exp<<<dim3(MAXT,8),256,0,stream>>>(table, hbb, HH, nullptr,
      W3T, (long)HH*HH, HH, HH, b3, HH, hba, HH);
  k_ln3<<<ATOT,256,0,stream>>>(hba, slots, g3, be3, aexp, atok, aslot, ap);
  k_comb<<<16384,256,0,stream>>>(slots, comb);
  k_gemm_go<<<dim3(32,4),256,0,stream>>>(comb, WoT, bo, obuf);
  k_lnout<<<NTOK,256,0,stream>>>(obuf, (float*)d_out, go, beo, entout);
}

// Round 8
// 520.543 us; speedup vs baseline: 1.0912x; 1.0912x over previous
//
#include <hip/hip_runtime.h>
#include <hip/hip_bf16.h>
#include <math.h>

typedef __hip_bfloat16 bf16;
typedef unsigned short u16;
typedef __attribute__((ext_vector_type(8))) short short8;
typedef __attribute__((ext_vector_type(4))) float f32x4;

#define NTOK 4096
#define DD   512
#define EE   8
#define DE   4096
#define HH   1024
#define OUTD 512
#define ATOT 8192
#define APAD 8320
#define MAXT 72
#define FCAP 1024
#define DMARGIN 1e-4
#define RSPLIT 4   // j-chunks per (token,expert) rescue pair

struct Tile { int e, row0, rows; };

__device__ __forceinline__ float b2f(u16 u){ return __uint_as_float(((unsigned)u)<<16); }

__device__ __forceinline__ float gelu_f(float x){
  return 0.5f * x * (1.0f + erff(x * 0.7071067811865476f));
}

__device__ __forceinline__ void gl2lds(const bf16* g, bf16* l){
  __builtin_amdgcn_global_load_lds((const __attribute__((address_space(1))) void*)g,
                                   (__attribute__((address_space(3))) void*)l, 16, 0, 0);
}

__device__ __forceinline__ f32x4 mfma16(short8 a, short8 b, f32x4 c){
  return __builtin_amdgcn_mfma_f32_16x16x32_bf16(a, b, c, 0, 0, 0);
}

// 128x128 tile, BK=32, 256 threads (4 waves, 64x64 quadrants, 4x4 mfma 16x16x32).
// LDS: row-major 32/row, XOR-swizzled 8-elem chunk (slot = kq ^ ((row>>1)&3)):
// coalesced staging (4 lanes cover one row's 64B) AND conflict-free ds_read_b128.
// 2-phase register-prefetch schedule (best-measured config; ~770 TF ≈ 85% of the
// 128² 2-barrier structural ceiling — m99-m141-class variants are proven null).
template<bool GATHER>
__device__ __forceinline__ void kloop(const bf16* __restrict__ A, int lda,
                                      const int* __restrict__ rowmap, int m0,
                                      const bf16* __restrict__ BT, int ldb, int n0,
                                      int K, bf16* As, bf16* Bs, f32x4 acc[4][4]){
  const int t = threadIdx.x;
  const int r = t>>2;
  const int sw = (t&3) ^ ((t>>3)&3);
  int ar0 = m0 + r, ar1 = m0 + 64 + r;
  if (GATHER){
    ar0 = rowmap[ar0 < ATOT ? ar0 : ATOT-1];
    ar1 = rowmap[ar1 < ATOT ? ar1 : ATOT-1];
  }
  const bf16* ap0 = A + (long)ar0*lda + sw*8;
  const bf16* ap1 = A + (long)ar1*lda + sw*8;
  const bf16* bp0 = BT + (long)(n0 + r)*ldb + sw*8;
  const bf16* bp1 = bp0 + (long)64*ldb;
  const int wave = t>>6, lane = t&63;
  const int qr = wave>>1, qc = wave&1, ln = lane&15, kq = lane>>4;
  const int slot = kq ^ ((ln>>1)&3);
  const bf16* ard = As + (qr*64 + ln)*32 + slot*8;
  const bf16* brd = Bs + (qc*64 + ln)*32 + slot*8;
  // prologue: stage k0 = 0
  gl2lds(ap0, As + t*8);
  gl2lds(ap1, As + 2048 + t*8);
  gl2lds(bp0, Bs + t*8);
  gl2lds(bp1, Bs + 2048 + t*8);
  for (int k0 = 0; k0 < K; k0 += 32){
    __syncthreads();                       // stage k0 landed (vmcnt drain)
    short8 a[4], b[4];
    #pragma unroll
    for (int i=0;i<4;i++) a[i] = *(const short8*)(ard + i*512);
    #pragma unroll
    for (int j=0;j<4;j++) b[j] = *(const short8*)(brd + j*512);
    __syncthreads();                       // reads done; LDS free for next stage
    int k1 = k0 + 32;
    if (k1 < K){
      gl2lds(ap0 + k1, As + t*8);
      gl2lds(ap1 + k1, As + 2048 + t*8);
      gl2lds(bp0 + k1, Bs + t*8);
      gl2lds(bp1 + k1, Bs + 2048 + t*8);
    }
    #pragma unroll
    for (int i=0;i<4;i++)
      #pragma unroll
      for (int j=0;j<4;j++)
        acc[i][j] = mfma16(a[i], b[j], acc[i][j]);
  }
}

// fused 2x2 split k-loop: stages Ah,Am,Bh,Bm once per k-chunk, accumulates
// hh + hm + mh in one pass; same 2-phase register-prefetch schedule.
__device__ __forceinline__ void kloop2(const bf16* __restrict__ A0, const bf16* __restrict__ A1,
                                       int lda, int m0,
                                       const bf16* __restrict__ B0, const bf16* __restrict__ B1,
                                       int ldb, int n0, int K,
                                       bf16* As0, bf16* As1, bf16* Bs0, bf16* Bs1,
                                       f32x4 acc[4][4]){
  const int t = threadIdx.x;
  const int r = t>>2;
  const int sw = (t&3) ^ ((t>>3)&3);
  const long aoff0 = (long)(m0 + r)*lda + sw*8;
  const long aoff1 = (long)(m0 + 64 + r)*lda + sw*8;
  const long boff0 = (long)(n0 + r)*ldb + sw*8;
  const long boff1 = boff0 + (long)64*ldb;
  const int wave = t>>6, lane = t&63;
  const int qr = wave>>1, qc = wave&1, ln = lane&15, kq = lane>>4;
  const int slot = kq ^ ((ln>>1)&3);
  const int ao = (qr*64 + ln)*32 + slot*8;
  const int bo = (qc*64 + ln)*32 + slot*8;
  // prologue: stage k0 = 0
  gl2lds(A0 + aoff0, As0 + t*8);
  gl2lds(A0 + aoff1, As0 + 2048 + t*8);
  gl2lds(A1 + aoff0, As1 + t*8);
  gl2lds(A1 + aoff1, As1 + 2048 + t*8);
  gl2lds(B0 + boff0, Bs0 + t*8);
  gl2lds(B0 + boff1, Bs0 + 2048 + t*8);
  gl2lds(B1 + boff0, Bs1 + t*8);
  gl2lds(B1 + boff1, Bs1 + 2048 + t*8);
  for (int k0 = 0; k0 < K; k0 += 32){
    __syncthreads();
    short8 a0[4], a1[4], b0[4], b1[4];
    #pragma unroll
    for (int i=0;i<4;i++){
      a0[i] = *(const short8*)(As0 + ao + i*512);
      a1[i] = *(const short8*)(As1 + ao + i*512);
    }
    #pragma unroll
    for (int j=0;j<4;j++){
      b0[j] = *(const short8*)(Bs0 + bo + j*512);
      b1[j] = *(const short8*)(Bs1 + bo + j*512);
    }
    __syncthreads();
    int k1 = k0 + 32;
    if (k1 < K){
      gl2lds(A0 + aoff0 + k1, As0 + t*8);
      gl2lds(A0 + aoff1 + k1, As0 + 2048 + t*8);
      gl2lds(A1 + aoff0 + k1, As1 + t*8);
      gl2lds(A1 + aoff1 + k1, As1 + 2048 + t*8);
      gl2lds(B0 + boff0 + k1, Bs0 + t*8);
      gl2lds(B0 + boff1 + k1, Bs0 + 2048 + t*8);
      gl2lds(B1 + boff0 + k1, Bs1 + t*8);
      gl2lds(B1 + boff1 + k1, Bs1 + 2048 + t*8);
    }
    #pragma unroll
    for (int i=0;i<4;i++)
      #pragma unroll
      for (int j=0;j<4;j++){
        acc[i][j] = mfma16(a0[i], b0[j], acc[i][j]);
        acc[i][j] = mfma16(a0[i], b1[j], acc[i][j]);
        acc[i][j] = mfma16(a1[i], b0[j], acc[i][j]);
      }
  }
}

// fused 3x3 split k-loop (6 combos: hh, hm, mh, hl, mm, lh); 2-phase prefetch.
__device__ __forceinline__ void kloop3(const bf16* __restrict__ A0, const bf16* __restrict__ A1,
                                       const bf16* __restrict__ A2, int lda, int m0,
                                       const bf16* __restrict__ B0, const bf16* __restrict__ B1,
                                       const bf16* __restrict__ B2, int ldb, int n0, int K,
                                       bf16* As0, bf16* As1, bf16* As2,
                                       bf16* Bs0, bf16* Bs1, bf16* Bs2,
                                       f32x4 acc[4][4]){
  const int t = threadIdx.x;
  const int r = t>>2;
  const int sw = (t&3) ^ ((t>>3)&3);
  const long aoff0 = (long)(m0 + r)*lda + sw*8;
  const long aoff1 = (long)(m0 + 64 + r)*lda + sw*8;
  const long boff0 = (long)(n0 + r)*ldb + sw*8;
  const long boff1 = boff0 + (long)64*ldb;
  const int wave = t>>6, lane = t&63;
  const int qr = wave>>1, qc = wave&1, ln = lane&15, kq = lane>>4;
  const int slot = kq ^ ((ln>>1)&3);
  const int ao = (qr*64 + ln)*32 + slot*8;
  const int bo = (qc*64 + ln)*32 + slot*8;
  // prologue: stage k0 = 0
  gl2lds(A0 + aoff0, As0 + t*8);
  gl2lds(A0 + aoff1, As0 + 2048 + t*8);
  gl2lds(A1 + aoff0, As1 + t*8);
  gl2lds(A1 + aoff1, As1 + 2048 + t*8);
  gl2lds(A2 + aoff0, As2 + t*8);
  gl2lds(A2 + aoff1, As2 + 2048 + t*8);
  gl2lds(B0 + boff0, Bs0 + t*8);
  gl2lds(B0 + boff1, Bs0 + 2048 + t*8);
  gl2lds(B1 + boff0, Bs1 + t*8);
  gl2lds(B1 + boff1, Bs1 + 2048 + t*8);
  gl2lds(B2 + boff0, Bs2 + t*8);
  gl2lds(B2 + boff1, Bs2 + 2048 + t*8);
  for (int k0 = 0; k0 < K; k0 += 32){
    __syncthreads();
    short8 a0[4], a1[4], a2[4], b0[4], b1[4], b2[4];
    #pragma unroll
    for (int i=0;i<4;i++){
      a0[i] = *(const short8*)(As0 + ao + i*512);
      a1[i] = *(const short8*)(As1 + ao + i*512);
      a2[i] = *(const short8*)(As2 + ao + i*512);
    }
    #pragma unroll
    for (int j=0;j<4;j++){
      b0[j] = *(const short8*)(Bs0 + bo + j*512);
      b1[j] = *(const short8*)(Bs1 + bo + j*512);
      b2[j] = *(const short8*)(Bs2 + bo + j*512);
    }
    __syncthreads();
    int k1 = k0 + 32;
    if (k1 < K){
      gl2lds(A0 + aoff0 + k1, As0 + t*8);
      gl2lds(A0 + aoff1 + k1, As0 + 2048 + t*8);
      gl2lds(A1 + aoff0 + k1, As1 + t*8);
      gl2lds(A1 + aoff1 + k1, As1 + 2048 + t*8);
      gl2lds(A2 + aoff0 + k1, As2 + t*8);
      gl2lds(A2 + aoff1 + k1, As2 + 2048 + t*8);
      gl2lds(B0 + boff0 + k1, Bs0 + t*8);
      gl2lds(B0 + boff1 + k1, Bs0 + 2048 + t*8);
      gl2lds(B1 + boff0 + k1, Bs1 + t*8);
      gl2lds(B1 + boff1 + k1, Bs1 + 2048 + t*8);
      gl2lds(B2 + boff0 + k1, Bs2 + t*8);
      gl2lds(B2 + boff1 + k1, Bs2 + 2048 + t*8);
    }
    #pragma unroll
    for (int i=0;i<4;i++)
      #pragma unroll
      for (int j=0;j<4;j++){
        acc[i][j] = mfma16(a0[i], b0[j], acc[i][j]);
        acc[i][j] = mfma16(a0[i], b1[j], acc[i][j]);
        acc[i][j] = mfma16(a1[i], b0[j], acc[i][j]);
        acc[i][j] = mfma16(a0[i], b2[j], acc[i][j]);
        acc[i][j] = mfma16(a1[i], b1[j], acc[i][j]);
        acc[i][j] = mfma16(a2[i], b0[j], acc[i][j]);
      }
  }
}

#define EPI_SETUP \
  const int t = threadIdx.x, wave=t>>6, lane=t&63; \
  const int qr=wave>>1, qc=wave&1, ln=lane&15, kq=lane>>4; (void)qr;

#define ACC_INIT \
  f32x4 acc[4][4]; \
  _Pragma("unroll") for (int i=0;i<4;i++) _Pragma("unroll") for (int j=0;j<4;j++) \
    acc[i][j] = (f32x4){0.f,0.f,0.f,0.f};

// ================= fused prep (one launch) =================
// ol == nullptr skips the low-limb store (xl is never consumed downstream).
__device__ __forceinline__ void split3_body(const float* __restrict__ in,
    bf16* __restrict__ oh, bf16* __restrict__ om, bf16* __restrict__ ol, int b, int n4){
  int i = b*256 + threadIdx.x;
  if (i >= n4) return;
  float4 v = ((const float4*)in)[i];
  float vv[4] = {v.x, v.y, v.z, v.w};
  u16 hs[4], ms[4], ls[4];
  #pragma unroll
  for (int c=0;c<4;c++){
    bf16 h = __float2bfloat16(vv[c]); float r1 = vv[c] - __bfloat162float(h);
    bf16 m = __float2bfloat16(r1);    float r2 = r1 - __bfloat162float(m);
    bf16 l = __float2bfloat16(r2);
    hs[c]=*(u16*)&h; ms[c]=*(u16*)&m; ls[c]=*(u16*)&l;
  }
  ((ushort4*)oh)[i] = (ushort4){hs[0],hs[1],hs[2],hs[3]};
  ((ushort4*)om)[i] = (ushort4){ms[0],ms[1],ms[2],ms[3]};
  if (ol) ((ushort4*)ol)[i] = (ushort4){ls[0],ls[1],ls[2],ls[3]};
}

__device__ __forceinline__ void tsplit3_body(const float* __restrict__ in,
    bf16* __restrict__ oh, bf16* __restrict__ om, bf16* __restrict__ ol,
    int R, int C, int bx, int by, float* tile /*[64][65]*/){
  int r0 = by*64, c0 = bx*64;
  int t = threadIdx.x, lr = t>>4, lc = (t&15)*4;
  #pragma unroll
  for (int it=0; it<4; it++){
    int rr = it*16 + lr;
    float4 v = *(const float4*)(in + (long)(r0+rr)*C + c0 + lc);
    tile[rr*65+lc]=v.x; tile[rr*65+lc+1]=v.y; tile[rr*65+lc+2]=v.z; tile[rr*65+lc+3]=v.w;
  }
  __syncthreads();
  #pragma unroll
  for (int it=0; it<4; it++){
    int cc = it*16 + lr;
    u16 hs[4], ms[4], ls[4];
    #pragma unroll
    for (int j=0;j<4;j++){
      float v = tile[(lc+j)*65+cc];
      bf16 h = __float2bfloat16(v); float r1 = v - __bfloat162float(h);
      bf16 m = __float2bfloat16(r1); float r2 = r1 - __bfloat162float(m);
      bf16 l = __float2bfloat16(r2);
      hs[j]=*(u16*)&h; ms[j]=*(u16*)&m; ls[j]=*(u16*)&l;
    }
    long oi = (long)(c0+cc)*R + r0 + lc;
    *(ushort4*)((u16*)oh + oi) = (ushort4){hs[0],hs[1],hs[2],hs[3]};
    *(ushort4*)((u16*)om + oi) = (ushort4){ms[0],ms[1],ms[2],ms[3]};
    *(ushort4*)((u16*)ol + oi) = (ushort4){ls[0],ls[1],ls[2],ls[3]};
  }
}

__device__ __forceinline__ void cvtT_body(const float* __restrict__ in,
    bf16* __restrict__ out, int R, int C, int bx, int by, int bz, float* tile){
  long zb = (long)bz * R * C;
  int r0 = by*64, c0 = bx*64;
  int t = threadIdx.x, lr = t>>4, lc = (t&15)*4;
  #pragma unroll
  for (int it=0; it<4; it++){
    int rr = it*16 + lr;
    float4 v = *(const float4*)(in + zb + (long)(r0+rr)*C + c0 + lc);
    tile[rr*65+lc]=v.x; tile[rr*65+lc+1]=v.y; tile[rr*65+lc+2]=v.z; tile[rr*65+lc+3]=v.w;
  }
  __syncthreads();
  #pragma unroll
  for (int it=0; it<4; it++){
    int cc = it*16 + lr;
    u16 hs[4];
    #pragma unroll
    for (int j=0;j<4;j++){
      bf16 h = __float2bfloat16(tile[(lc+j)*65+cc]);
      hs[j]=*(u16*)&h;
    }
    *(ushort4*)((u16*)out + zb + (long)(c0+cc)*R + r0 + lc) = (ushort4){hs[0],hs[1],hs[2],hs[3]};
  }
}

__device__ __forceinline__ void cvec_body(const float* __restrict__ bmap,
    const float* __restrict__ Wr, const float* __restrict__ br, float* __restrict__ cvec, int b){
  int id = b*256 + threadIdx.x;   // (e,j)
  int e = id >> 9, j = id & 511;
  float s = 0.f;
  for (int k=0;k<512;k++) s += bmap[e*512+k] * Wr[k*512 + j];
  cvec[id] = s + br[j];
}

__global__ __launch_bounds__(256) void k_prep(const float* __restrict__ x,
    const float* __restrict__ Wmap, const float* __restrict__ Wr,
    const float* __restrict__ bmap, const float* __restrict__ br,
    const float* __restrict__ W1, const float* __restrict__ W2,
    const float* __restrict__ W3, const float* __restrict__ Wo,
    bf16* xh, bf16* xm,
    bf16* Wm_h, bf16* Wm_m, bf16* Wm_l,
    bf16* WrT_h, bf16* WrT_m, bf16* WrT_l, float* cvec,
    bf16* W1T, bf16* W2T, bf16* W3T, bf16* WoT){
  __shared__ float tile[64*65];
  int b = blockIdx.x;
  if (b < 2048){ split3_body(x, xh, xm, nullptr, b, 524288); return; }
  b -= 2048;
  if (b < 2048){ split3_body(Wmap, Wm_h, Wm_m, Wm_l, b, 524288); return; }
  b -= 2048;
  if (b < 64){ tsplit3_body(Wr, WrT_h, WrT_m, WrT_l, 512, 512, b&7, b>>3, tile); return; }
  b -= 64;
  if (b < 16){ cvec_body(bmap, Wr, br, cvec, b); return; }
  b -= 16;
  if (b < 1024){ cvtT_body(W1, W1T, 512, 1024, b&15, (b>>4)&7, b>>7, tile); return; }
  b -= 1024;
  if (b < 2048){ cvtT_body(W2, W2T, 1024, 1024, b&15, (b>>4)&15, b>>8, tile); return; }
  b -= 2048;
  if (b < 2048){ cvtT_body(W3, W3T, 1024, 1024, b&15, (b>>4)&15, b>>8, tile); return; }
  b -= 2048;
  cvtT_body(Wo, WoT, 1024, 512, b&7, b>>3, 0, tile);
}
#define PREP_BLOCKS 9424

// ---- MT_e[j,d] = sum_k Wr[k,j] * Wmap[d, e*512+k] — fused 6-combo single k-loop
__global__ __launch_bounds__(256) void k_gemm_MT(
    const bf16* __restrict__ Rh, const bf16* __restrict__ Rm, const bf16* __restrict__ Rl,
    const bf16* __restrict__ Wh, const bf16* __restrict__ Wm, const bf16* __restrict__ Wl,
    bf16* __restrict__ MTh, bf16* __restrict__ MTm, float* __restrict__ M32){
  __shared__ __align__(16) bf16 As0[4096], As1[4096], As2[4096],
                                Bs0[4096], Bs1[4096], Bs2[4096];
  int m0 = blockIdx.x*128, n0 = blockIdx.y*128, e = blockIdx.z;
  ACC_INIT
  kloop3(Rh, Rm, Rl, 512, m0, Wh + e*512, Wm + e*512, Wl + e*512, DE, n0, 512,
         As0, As1, As2, Bs0, Bs1, Bs2, acc);
  EPI_SETUP
  int cg[4];
  #pragma unroll
  for (int j=0;j<4;j++) cg[j] = n0 + qc*64 + j*16 + ln;
  long eb = (long)e*512*512;
  #pragma unroll
  for (int i=0;i<4;i++)
    #pragma unroll
    for (int r=0;r<4;r++){
      long base = eb + (long)(m0 + qr*64 + i*16 + kq*4 + r) * 512;
      #pragma unroll
      for (int j=0;j<4;j++){
        float v = acc[i][j][r];
        bf16 h = __float2bfloat16(v); float r1 = v - __bfloat162float(h);
        bf16 m = __float2bfloat16(r1);
        MTh[base + cg[j]] = h; MTm[base + cg[j]] = m; M32[base + cg[j]] = v;
      }
    }
}

// ---- re = x @ MT_e^T + c_e — fused 3-combo (hh+hm+mh) single k-loop;
// epilogue: dist2[n,e] += (x-re)^2 in fp64
__global__ __launch_bounds__(256) void k_gemm_re(
    const bf16* __restrict__ xh, const bf16* __restrict__ xm,
    const bf16* __restrict__ MTh, const bf16* __restrict__ MTm,
    const float* __restrict__ cvec, const float* __restrict__ x, double* __restrict__ dist2){
  __shared__ __align__(16) bf16 As0[4096], As1[4096], Bs0[4096], Bs1[4096];
  int m0 = blockIdx.x*128, n0 = blockIdx.y*128, e = blockIdx.z;
  ACC_INIT
  long eb = (long)e*512*512;
  kloop2(xh, xm, 512, m0, MTh + eb, MTm + eb, 512, n0, 512,
         As0, As1, Bs0, Bs1, acc);
  EPI_SETUP
  int cg[4]; float cv[4];
  #pragma unroll
  for (int j=0;j<4;j++){ cg[j] = n0 + qc*64 + j*16 + ln; cv[j] = cvec[e*512 + cg[j]]; }
  #pragma unroll
  for (int i=0;i<4;i++)
    #pragma unroll
    for (int r=0;r<4;r++){
      int rg = m0 + qr*64 + i*16 + kq*4 + r;      // token index
      const float* xr = x + (long)rg*512;
      double s = 0.0;
      #pragma unroll
      for (int j=0;j<4;j++){
        float re = acc[i][j][r] + cv[j];
        float d  = xr[cg[j]] - re;
        s += (double)d * (double)d;
      }
      s += __shfl_xor(s,1); s += __shfl_xor(s,2); s += __shfl_xor(s,4); s += __shfl_xor(s,8);
      if (ln == 0) atomicAdd(&dist2[(long)rg*EE + e], s);
    }
}

// ---- expert GEMM (ragged tile table, optional gather), gelu epilogue, fp32 bias
__global__ __launch_bounds__(256) void k_gemm_exp(const Tile* __restrict__ table,
    const bf16* __restrict__ A, int lda, const int* __restrict__ rowmap,
    const bf16* __restrict__ Wt, long wstride, int ldb, int K,
    const float* __restrict__ bias, int ncols, bf16* __restrict__ out, int ldo){
  Tile tc = table[blockIdx.x];
  if (tc.e < 0) return;
  __shared__ __align__(16) bf16 As[4096], Bs[4096];
  int n0 = blockIdx.y*128;
  ACC_INIT
  const bf16* BT = Wt + (long)tc.e*wstride;
  if (rowmap) kloop<true >(A, lda, rowmap, tc.row0, BT, ldb, n0, K, As, Bs, acc);
  else        kloop<false>(A, lda, nullptr, tc.row0, BT, ldb, n0, K, As, Bs, acc);
  EPI_SETUP
  const float* bp = bias + (long)tc.e*ncols;
  int cg[4]; float bv[4];
  #pragma unroll
  for (int j=0;j<4;j++){ cg[j] = n0 + qc*64 + j*16 + ln; bv[j] = bp[cg[j]]; }
  #pragma unroll
  for (int i=0;i<4;i++)
    #pragma unroll
    for (int r=0;r<4;r++){
      int rl = qr*64 + i*16 + kq*4 + r;
      if (rl < tc.rows){
        bf16* op = out + (long)(tc.row0 + rl)*ldo;
        #pragma unroll
        for (int j=0;j<4;j++)
          op[cg[j]] = __float2bfloat16(gelu_f(acc[i][j][r] + bv[j]));
      }
    }
}

// ---- out-proj GEMM: obuf = gelu(comb @ Wo + bo)
__global__ __launch_bounds__(256) void k_gemm_go(const bf16* __restrict__ A,
    const bf16* __restrict__ WoT, const float* __restrict__ bias, bf16* __restrict__ out){
  __shared__ __align__(16) bf16 As[4096], Bs[4096];
  int m0 = blockIdx.x*128, n0 = blockIdx.y*128;
  ACC_INIT
  kloop<false>(A, HH, nullptr, m0, WoT, HH, n0, HH, As, Bs, acc);
  EPI_SETUP
  int cg[4]; float bv[4];
  #pragma unroll
  for (int j=0;j<4;j++){ cg[j] = n0 + qc*64 + j*16 + ln; bv[j] = bias[cg[j]]; }
  #pragma unroll
  for (int i=0;i<4;i++)
    #pragma unroll
    for (int r=0;r<4;r++){
      long base = (long)(m0 + qr*64 + i*16 + kq*4 + r) * OUTD;
      #pragma unroll
      for (int j=0;j<4;j++)
        out[base + cg[j]] = __float2bfloat16(gelu_f(acc[i][j][r] + bv[j]));
    }
}

// ---- router select (fp64): top-2 LARGEST dist; flags low-margin tokens for rescue
__global__ __launch_bounds__(256) void k_select(const double* __restrict__ dist2,
    float* __restrict__ selp, int* __restrict__ seli, int* __restrict__ counts,
    float* __restrict__ entacc, int* __restrict__ flaglist, int* __restrict__ nflag){
  __shared__ int hc[EE];
  int t = threadIdx.x;
  if (t < EE) hc[t] = 0;
  __syncthreads();
  int n = blockIdx.x*256 + t;
  double d0 = -1.0, d1 = -1.0, d2 = -1.0; int i0 = 0, i1 = 0;
  #pragma unroll
  for (int e=0;e<EE;e++){
    double d = sqrt(dist2[(long)n*EE + e]);
    if (d > d0){ d2 = d1; d1 = d0; i1 = i0; d0 = d; i0 = e; }
    else if (d > d1){ d2 = d1; d1 = d; i1 = e; }
    else if (d > d2){ d2 = d; }
  }
  if (d1 - d2 < DMARGIN){ int p = atomicAdd(nflag, 1); flaglist[p & (FCAP-1)] = n; }
  double s0 = exp(-d0), s1 = exp(-d1);   // s0 = smallest sim -> slot 0
  double den = s0 + s1;
  float p0 = (float)(s0/den), p1 = (float)(s1/den);
  selp[2*n] = p0; selp[2*n+1] = p1;
  seli[2*n] = i0; seli[2*n+1] = i1;
  atomicAdd(&hc[i0], 1); atomicAdd(&hc[i1], 1);
  float a0 = p0, a1 = p1;
  float a2 = p0*logf(p0+1e-6f) + p1*logf(p1+1e-6f);
  #pragma unroll
  for (int m=32;m;m>>=1){ a0 += __shfl_down(a0,m); a1 += __shfl_down(a1,m); a2 += __shfl_down(a2,m); }
  if ((t&63)==0){ atomicAdd(&entacc[0], a0); atomicAdd(&entacc[1], a1); atomicAdd(&entacc[2], a2); }
  __syncthreads();
  if (t < EE) atomicAdd(&counts[t], hc[t]);
}

// ---- rescue: one (flagged-token, expert, j-chunk) work item per block iteration.
// Each pair is split over RSPLIT=4 blocks (128 rows each); each wave handles 32
// rows, batched 8 rows per shuffle-reduce round so 16 float4 loads are in flight
// at once. Partial sums land in rbuf4[pid*RSPLIT + chunk]; k_scan sums the chunks.
__global__ __launch_bounds__(256) void k_rescue(const int* __restrict__ flaglist,
    const int* __restrict__ nflag, const float* __restrict__ x,
    const float* __restrict__ M32, const float* __restrict__ cvec,
    double* __restrict__ rbuf4){
  __shared__ float xs[512];
  __shared__ double wsum[4];
  int t = threadIdx.x, w = t>>6, l = t&63;
  int nf = *nflag; if (nf > FCAP) nf = FCAP;
  int work = nf * EE * RSPLIT;
  for (int wid = blockIdx.x; wid < work; wid += gridDim.x){
    int pid = wid >> 2, chunk = wid & (RSPLIT-1);
    int f = pid >> 3, e = pid & 7;
    int n = flaglist[f];
    xs[t] = x[(long)n*512 + t]; xs[t+256] = x[(long)n*512 + 256 + t];
    __syncthreads();
    const float* Me = M32 + ((long)e << 18);
    const float* xp = xs + l*8;
    float x0=xp[0], x1=xp[1], x2=xp[2], x3=xp[3], x4=xp[4], x5=xp[5], x6=xp[6], x7=xp[7];
    double s = 0.0;
    int j0 = chunk*128 + w*32;
    for (int rb = 0; rb < 32; rb += 8){
      double d[8];
      #pragma unroll
      for (int rr=0; rr<8; rr++){
        const float* Mr = Me + (long)(j0 + rb + rr)*512 + l*8;
        float4 a = *(const float4*)Mr, b = *(const float4*)(Mr+4);
        d[rr] = (double)a.x*x0 + (double)a.y*x1 + (double)a.z*x2 + (double)a.w*x3
              + (double)b.x*x4 + (double)b.y*x5 + (double)b.z*x6 + (double)b.w*x7;
      }
      #pragma unroll
      for (int m=32;m;m>>=1){
        #pragma unroll
        for (int rr=0; rr<8; rr++) d[rr] += __shfl_down(d[rr], m);
      }
      if (l == 0){
        #pragma unroll
        for (int rr=0; rr<8; rr++){
          int j = j0 + rb + rr;
          double diff = (double)xs[j] - (d[rr] + (double)cvec[e*512 + j]);
          s += diff*diff;
        }
      }
    }
    if (l == 0) wsum[w] = s;
    __syncthreads();
    if (t == 0) rbuf4[wid] = wsum[0]+wsum[1]+wsum[2]+wsum[3];
    __syncthreads();
  }
}

// ---- merged: rescue patch (parallel) + tile-table scan (thread 0)
__global__ __launch_bounds__(256) void k_scan(const int* __restrict__ flaglist,
    const int* __restrict__ nflag, const double* __restrict__ rbuf4,
    float* __restrict__ selp, int* __restrict__ seli,
    int* __restrict__ counts, float* __restrict__ entacc,
    int* __restrict__ cursors, Tile* __restrict__ table, float* __restrict__ entout){
  int t = threadIdx.x;
  int nf = *nflag; if (nf > FCAP) nf = FCAP;
  for (int idx = t; idx < nf; idx += 256){
    int n = flaglist[idx];
    double d0=-1.0, d1=-1.0; int i0=0, i1=0;
    #pragma unroll
    for (int e=0;e<EE;e++){
      const double* rp = rbuf4 + ((long)(idx*EE + e))*RSPLIT;
      double d = sqrt(rp[0] + rp[1] + rp[2] + rp[3]);
      if (d > d0){ d1=d0; i1=i0; d0=d; i0=e; }
      else if (d > d1){ d1=d; i1=e; }
    }
    double s0 = exp(-d0), s1 = exp(-d1), den = s0+s1;
    float p0 = (float)(s0/den), p1 = (float)(s1/den);
    int o0 = seli[2*n], o1 = seli[2*n+1];
    float q0 = selp[2*n], q1 = selp[2*n+1];
    if (o0 != i0 || o1 != i1){
      atomicSub(&counts[o0], 1); atomicSub(&counts[o1], 1);
      atomicAdd(&counts[i0], 1); atomicAdd(&counts[i1], 1);
      seli[2*n] = i0; seli[2*n+1] = i1;
    }
    atomicAdd(&entacc[0], p0 - q0);
    atomicAdd(&entacc[1], p1 - q1);
    atomicAdd(&entacc[2], (p0*logf(p0+1e-6f) + p1*logf(p1+1e-6f))
                        - (q0*logf(q0+1e-6f) + q1*logf(q1+1e-6f)));
    selp[2*n] = p0; selp[2*n+1] = p1;
  }
  __threadfence();
  __syncthreads();
  if (t != 0) return;
  int off = 0, ti = 0;
  for (int e=0;e<EE;e++){
    cursors[e] = off;
    int c = counts[e];
    for (int r=0;r<c;r+=128){
      table[ti].e = e; table[ti].row0 = off + r;
      table[ti].rows = (c - r < 128) ? (c - r) : 128; ti++;
    }
    off += c;
  }
  for (; ti<MAXT; ti++){ table[ti].e = -1; table[ti].row0 = 0; table[ti].rows = 0; }
  float pm0 = entacc[0] * (1.0f/NTOK), pm1 = entacc[1] * (1.0f/NTOK);
  *entout = pm0*logf(pm0 + 1e-6f) + pm1*logf(pm1 + 1e-6f) - entacc[2] * (1.0f/NTOK);
}

__global__ __launch_bounds__(256) void k_place(const int* __restrict__ seli,
    const float* __restrict__ selp, int* __restrict__ cursors,
    int* __restrict__ atok, float* __restrict__ ap, int* __restrict__ aslot,
    int* __restrict__ aexp){
  int id = blockIdx.x*256 + threadIdx.x;   // 8192 = (token, slot)
  int e = seli[id];
  int pos = atomicAdd(&cursors[e], 1);
  atok[pos] = id >> 1;
  ap[pos]   = selp[id];
  aslot[pos]= id & 1;
  aexp[pos] = e;
}

__device__ __forceinline__ void blkred2(float& s, float& q, int t){
  #pragma unroll
  for (int m=32;m;m>>=1){ s += __shfl_down(s,m); q += __shfl_down(q,m); }
  __shared__ float shs[4], shq[4];
  if ((t&63)==0){ shs[t>>6] = s; shq[t>>6] = q; }
  __syncthreads();
  s = shs[0]+shs[1]+shs[2]+shs[3];
  q = shq[0]+shq[1]+shq[2]+shq[3];
}

// ---- LayerNorm over H=1024 per assignment row, per-expert fp32 gamma/beta
__global__ __launch_bounds__(256) void k_ln_mid(const bf16* __restrict__ in, bf16* __restrict__ out,
    const float* __restrict__ g, const float* __restrict__ be, const int* __restrict__ aexp){
  int row = blockIdx.x, t = threadIdx.x;
  const ushort4 u = *(const ushort4*)((const u16*)in + (long)row*HH + t*4);
  float v0=b2f(u.x), v1=b2f(u.y), v2=b2f(u.z), v3=b2f(u.w);
  float s = v0+v1+v2+v3;
  float q = v0*v0+v1*v1+v2*v2+v3*v3;
  blkred2(s, q, t);
  float mu = s*(1.0f/HH);
  float rs = rsqrtf(q*(1.0f/HH) - mu*mu + 1e-5f);
  int e = aexp[row];
  const float4 ug = *(const float4*)(g  + (long)e*HH + t*4);
  const float4 ub = *(const float4*)(be + (long)e*HH + t*4);
  bf16* op = out + (long)row*HH + t*4;
  op[0] = __float2bfloat16((v0-mu)*rs*ug.x + ub.x);
  op[1] = __float2bfloat16((v1-mu)*rs*ug.y + ub.y);
  op[2] = __float2bfloat16((v2-mu)*rs*ug.z + ub.z);
  op[3] = __float2bfloat16((v3-mu)*rs*ug.w + ub.w);
}

// ---- LN3 + gate multiply + scatter to per-slot fp32 buffer
__global__ __launch_bounds__(256) void k_ln3(const bf16* __restrict__ in, float* __restrict__ slots,
    const float* __restrict__ g, const float* __restrict__ be, const int* __restrict__ aexp,
    const int* __restrict__ atok, const int* __restrict__ aslot, const float* __restrict__ ap){
  int row = blockIdx.x, t = threadIdx.x;
  const ushort4 u = *(const ushort4*)((const u16*)in + (long)row*HH + t*4);
  float v0=b2f(u.x), v1=b2f(u.y), v2=b2f(u.z), v3=b2f(u.w);
  float s = v0+v1+v2+v3;
  float q = v0*v0+v1*v1+v2*v2+v3*v3;
  blkred2(s, q, t);
  float mu = s*(1.0f/HH);
  float rs = rsqrtf(q*(1.0f/HH) - mu*mu + 1e-5f);
  int e = aexp[row];
  const float4 ug = *(const float4*)(g  + (long)e*HH + t*4);
  const float4 ub = *(const float4*)(be + (long)e*HH + t*4);
  float p = ap[row];
  float* op = slots + ((long)atok[row]*2 + aslot[row])*HH + t*4;
  op[0] = p*((v0-mu)*rs*ug.x + ub.x);
  op[1] = p*((v1-mu)*rs*ug.y + ub.y);
  op[2] = p*((v2-mu)*rs*ug.z + ub.z);
  op[3] = p*((v3-mu)*rs*ug.w + ub.w);
}

// ---- combine: comb[n,c] = bf16(slots[n,0,c] + slots[n,1,c]) — float4 vectorized
__global__ __launch_bounds__(256) void k_comb(const float* __restrict__ slots, bf16* __restrict__ comb){
  long i = ((long)blockIdx.x*256 + threadIdx.x) * 4;
  long n = i >> 10, c = i & 1023;
  const float4 a = *(const float4*)(slots + n*2*HH + c);
  const float4 b = *(const float4*)(slots + (n*2+1)*HH + c);
  bf16 o0 = __float2bfloat16(a.x + b.x);
  bf16 o1 = __float2bfloat16(a.y + b.y);
  bf16 o2 = __float2bfloat16(a.z + b.z);
  bf16 o3 = __float2bfloat16(a.w + b.w);
  *(ushort4*)((u16*)comb + i) = (ushort4){*(u16*)&o0, *(u16*)&o1, *(u16*)&o2, *(u16*)&o3};
}

// ---- final LN over OUT=512 -> d_out (fp32); also writes ent_loss
__global__ __launch_bounds__(256) void k_lnout(const bf16* __restrict__ in, float* __restrict__ dout,
    const float* __restrict__ g, const float* __restrict__ be, const float* __restrict__ entout){
  int row = blockIdx.x, t = threadIdx.x;
  const bf16* ip = in + (long)row*OUTD + t*2;
  float v0 = __bfloat162float(ip[0]), v1 = __bfloat162float(ip[1]);
  float s = v0+v1, q = v0*v0+v1*v1;
  blkred2(s, q, t);
  float mu = s*(1.0f/OUTD);
  float rs = rsqrtf(q*(1.0f/OUTD) - mu*mu + 1e-5f);
  float g0 = g[t*2], g1v = g[t*2+1];
  float b0 = be[t*2], b1v = be[t*2+1];
  float* op = dout + (long)row*OUTD + t*2;
  op[0] = (v0-mu)*rs*g0 + b0;
  op[1] = (v1-mu)*rs*g1v + b1v;
  if (row==0 && t==0) dout[(long)NTOK*OUTD] = *entout;
}

extern "C" void kernel_launch(void* const* d_in, const int* in_sizes, int n_in,
                              void* d_out, int out_size, void* d_ws, size_t ws_size,
                              hipStream_t stream){
  (void)in_sizes; (void)n_in; (void)out_size; (void)ws_size;
  const float* x    = (const float*)d_in[0];
  const float* Wmap = (const float*)d_in[1];
  const float* bmap = (const float*)d_in[2];
  const float* Wr   = (const float*)d_in[3];
  const float* br   = (const float*)d_in[4];
  const float* W1   = (const float*)d_in[5];
  const float* b1   = (const float*)d_in[6];
  const float* g1   = (const float*)d_in[7];
  const float* be1  = (const float*)d_in[8];
  const float* W2   = (const float*)d_in[9];
  const float* b2   = (const float*)d_in[10];
  const float* g2   = (const float*)d_in[11];
  const float* be2  = (const float*)d_in[12];
  const float* W3   = (const float*)d_in[13];
  const float* b3   = (const float*)d_in[14];
  const float* g3   = (const float*)d_in[15];
  const float* be3  = (const float*)d_in[16];
  const float* Wo   = (const float*)d_in[17];
  const float* bo   = (const float*)d_in[18];
  const float* go   = (const float*)d_in[19];
  const float* beo  = (const float*)d_in[20];

  char* ws = (char*)d_ws;
  size_t o = 0;
  auto take = [&](size_t b){ size_t r = o; o += (b + 255) & ~(size_t)255; return r; };
  size_t o_xh   = take((size_t)NTOK*DD*2);     // bf16(x); also expert-GEMM1 A
  size_t o_xm   = take((size_t)NTOK*DD*2);     // comb overlays xm+xl
  size_t o_xl   = take((size_t)NTOK*DD*2);     // reserved (comb overlay); xl store skipped
  size_t o_R1   = take((size_t)APAD*HH*2);     // phase1: Wmap splits + WrT splits + cvec; phase2: hba
  size_t o_R2   = take((size_t)APAD*HH*2);     // phase1: MTh+MTm+M32;                    phase2: hbb
  size_t o_W1T  = take((size_t)EE*HH*DD*2);    // obuf overlays front half
  size_t o_W2T  = take((size_t)EE*HH*HH*2);    // slots overlays W2T+W3T (exactly 32 MB)
  size_t o_W3T  = take((size_t)EE*HH*HH*2);
  size_t o_WoT  = take((size_t)OUTD*HH*2);
  size_t o_dist2= take((size_t)NTOK*EE*8);     // zeroed (fp64)
  size_t o_cnt  = take(64);                    // zeroed
  size_t o_ent  = take(64);                    // zeroed
  size_t o_nfl  = take(64);                    // zeroed
  size_t o_cur  = take(64);
  size_t o_eout = take(64);
  size_t o_flag = take((size_t)FCAP*4);
  size_t o_rbuf = take((size_t)FCAP*EE*RSPLIT*8);
  size_t o_selp = take((size_t)NTOK*2*4);
  size_t o_seli = take((size_t)NTOK*2*4);
  size_t o_atok = take((size_t)ATOT*4);
  size_t o_ap   = take((size_t)ATOT*4);
  size_t o_aslt = take((size_t)ATOT*4);
  size_t o_aexp = take((size_t)ATOT*4);
  size_t o_tab  = take((size_t)MAXT*sizeof(Tile));
  (void)o_xl;

  bf16* xh=(bf16*)(ws+o_xh); bf16* xm=(bf16*)(ws+o_xm);
  // R1 sub-layout (phase 1)
  bf16* Wm_h=(bf16*)(ws+o_R1);
  bf16* Wm_m=(bf16*)(ws+o_R1+ 4194304);
  bf16* Wm_l=(bf16*)(ws+o_R1+ 8388608);
  bf16* WrT_h=(bf16*)(ws+o_R1+12582912);
  bf16* WrT_m=(bf16*)(ws+o_R1+13107200);
  bf16* WrT_l=(bf16*)(ws+o_R1+13631488);
  float* cvec=(float*)(ws+o_R1+14155776);
  // R2 sub-layout (phase 1): MTh (4MB) + MTm (4MB) + M32 fp32 (8MB) = 16MB <= 17MB
  bf16* MT_h=(bf16*)(ws+o_R2);
  bf16* MT_m=(bf16*)(ws+o_R2+4194304);
  float* M32=(float*)(ws+o_R2+8388608);
  // phase-2 overlays
  bf16* hba=(bf16*)(ws+o_R1);
  bf16* hbb=(bf16*)(ws+o_R2);
  bf16* W1T=(bf16*)(ws+o_W1T); bf16* W2T=(bf16*)(ws+o_W2T); bf16* W3T=(bf16*)(ws+o_W3T);
  bf16* WoT=(bf16*)(ws+o_WoT);
  float* slots=(float*)(ws+o_W2T);             // 32 MB = W2T+W3T
  bf16* comb=(bf16*)(ws+o_xm);                 // 8 MB = xm+xl
  bf16* obuf=(bf16*)(ws+o_W1T);                // 4 MB of W1T
  double* dist2=(double*)(ws+o_dist2);
  int* counts=(int*)(ws+o_cnt); float* entacc=(float*)(ws+o_ent);
  int* nflag=(int*)(ws+o_nfl);
  int* cursors=(int*)(ws+o_cur); float* entout=(float*)(ws+o_eout);
  int* flaglist=(int*)(ws+o_flag);
  double* rbuf4=(double*)(ws+o_rbuf);
  float* selp=(float*)(ws+o_selp); int* seli=(int*)(ws+o_seli);
  int* atok=(int*)(ws+o_atok); float* ap=(float*)(ws+o_ap);
  int* aslot=(int*)(ws+o_aslt); int* aexp=(int*)(ws+o_aexp);
  Tile* table=(Tile*)(ws+o_tab);

  hipMemsetAsync(ws + o_dist2, 0, (o_nfl + 64) - o_dist2, stream);

  // fused convert / split / transpose (one launch)
  k_prep<<<PREP_BLOCKS,256,0,stream>>>(x, Wmap, Wr, bmap, br, W1, W2, W3, Wo,
      xh, xm, Wm_h, Wm_m, Wm_l, WrT_h, WrT_m, WrT_l, cvec, W1T, W2T, W3T, WoT);

  // router
  k_gemm_MT<<<dim3(4,4,8),256,0,stream>>>(WrT_h, WrT_m, WrT_l, Wm_h, Wm_m, Wm_l,
                                          MT_h, MT_m, M32);
  k_gemm_re<<<dim3(32,4,8),256,0,stream>>>(xh, xm, MT_h, MT_m, cvec, x, dist2);
  k_select<<<16,256,0,stream>>>(dist2, selp, seli, counts, entacc, flaglist, nflag);
  k_rescue<<<2048,256,0,stream>>>(flaglist, nflag, x, M32, cvec, rbuf4);
  k_scan<<<1,256,0,stream>>>(flaglist, nflag, rbuf4, selp, seli, counts, entacc,
                             cursors, table, entout);
  k_place<<<32,256,0,stream>>>(seli, selp, cursors, atok, ap, aslot, aexp);

  // expert MLP (sparse, N*K = 8192 rows)
  k_gemm_exp<<<dim3(MAXT,8),256,0,stream>>>(table, xh, DD, atok,
      W1T, (long)HH*DD, DD, DD, b1, HH, hba, HH);
  k_ln_mid<<<ATOT,256,0,stream>>>(hba, hbb, g1, be1, aexp);
  k_gemm_exp<<<dim3(MAXT,8),256,0,stream>>>(table, hbb, HH, nullptr,
      W2T, (long)HH*HH, HH, HH, b2, HH, hba, HH);
  k_ln_mid<<<ATOT,256,0,stream>>>(hba, hbb, g2, be2, aexp);
  k_gemm_exp<<<dim3(MAXT,8),256,0,stream>>>(table, hbb, HH, nullptr,
      W3T, (long)HH*HH, HH, HH, b3, HH, hba, HH);
  k_ln3<<<ATOT,256,0,stream>>>(hba, slots, g3, be3, aexp, atok, aslot, ap);
  k_comb<<<4096,256,0,stream>>>(slots, comb);
  k_gemm_go<<<dim3(32,4),256,0,stream>>>(comb, WoT, bo, obuf);
  k_lnout<<<NTOK,256,0,stream>>>(obuf, (float*)d_out, go, beo, entout);
}

// Round 9
// 518.587 us; speedup vs baseline: 1.0953x; 1.0038x over previous
//
#include <hip/hip_runtime.h>
#include <hip/hip_bf16.h>
#include <math.h>

typedef __hip_bfloat16 bf16;
typedef unsigned short u16;
typedef __attribute__((ext_vector_type(8))) short short8;
typedef __attribute__((ext_vector_type(4))) float f32x4;

#define NTOK 4096
#define DD   512
#define EE   8
#define DE   4096
#define HH   1024
#define OUTD 512
#define ATOT 8192
#define APAD 8320
#define MAXT 72
#define FCAP 1024
#define DMARGIN 1e-4
#define RSPLIT 4   // j-chunks per (token,expert) rescue pair

struct Tile { int e, row0, rows; };

__device__ __forceinline__ float b2f(u16 u){ return __uint_as_float(((unsigned)u)<<16); }

__device__ __forceinline__ float gelu_f(float x){
  return 0.5f * x * (1.0f + erff(x * 0.7071067811865476f));
}

__device__ __forceinline__ void gl2lds(const bf16* g, bf16* l){
  __builtin_amdgcn_global_load_lds((const __attribute__((address_space(1))) void*)g,
                                   (__attribute__((address_space(3))) void*)l, 16, 0, 0);
}

__device__ __forceinline__ f32x4 mfma16(short8 a, short8 b, f32x4 c){
  return __builtin_amdgcn_mfma_f32_16x16x32_bf16(a, b, c, 0, 0, 0);
}

// 128x128 tile, BK=64 (two 32-wide sub-slabs per barrier pair), 256 threads
// (4 waves, 64x64 quadrants, 4x4 mfma 16x16x32). LDS: two side-by-side 32-wide
// tiles, row-major 32/row, XOR-swizzled 8-elem chunk (slot = kq ^ ((row>>1)&3)).
// Halving the barrier count vs BK=32 halves the number of exposed vmcnt-drain
// latencies (drain is latency-dominated, not load-count-dominated); LDS stays
// 32 KB/block so the m132 BK=128 occupancy cliff is avoided. MFMA order is
// k-ascending — bit-identical to the BK=32 version.
template<bool GATHER>
__device__ __forceinline__ void kloop(const bf16* __restrict__ A, int lda,
                                      const int* __restrict__ rowmap, int m0,
                                      const bf16* __restrict__ BT, int ldb, int n0,
                                      int K, bf16 (*As)[4096], bf16 (*Bs)[4096],
                                      f32x4 acc[4][4]){
  const int t = threadIdx.x;
  const int r = t>>2;
  const int sw = (t&3) ^ ((t>>3)&3);
  int ar0 = m0 + r, ar1 = m0 + 64 + r;
  if (GATHER){
    ar0 = rowmap[ar0 < ATOT ? ar0 : ATOT-1];
    ar1 = rowmap[ar1 < ATOT ? ar1 : ATOT-1];
  }
  const bf16* ap0 = A + (long)ar0*lda + sw*8;
  const bf16* ap1 = A + (long)ar1*lda + sw*8;
  const bf16* bp0 = BT + (long)(n0 + r)*ldb + sw*8;
  const bf16* bp1 = bp0 + (long)64*ldb;
  const int wave = t>>6, lane = t&63;
  const int qr = wave>>1, qc = wave&1, ln = lane&15, kq = lane>>4;
  const int slot = kq ^ ((ln>>1)&3);
  const int ao = (qr*64 + ln)*32 + slot*8;
  const int bo = (qc*64 + ln)*32 + slot*8;
  // prologue: stage both sub-slabs of k0 = 0
  #pragma unroll
  for (int s=0;s<2;s++){
    gl2lds(ap0 + s*32, As[s] + t*8);
    gl2lds(ap1 + s*32, As[s] + 2048 + t*8);
    gl2lds(bp0 + s*32, Bs[s] + t*8);
    gl2lds(bp1 + s*32, Bs[s] + 2048 + t*8);
  }
  for (int k0 = 0; k0 < K; k0 += 64){
    __syncthreads();                       // stage k0 slab landed (vmcnt drain)
    short8 a0[4], b0[4], a1[4], b1[4];
    #pragma unroll
    for (int i=0;i<4;i++){
      a0[i] = *(const short8*)(As[0] + ao + i*512);
      a1[i] = *(const short8*)(As[1] + ao + i*512);
    }
    #pragma unroll
    for (int j=0;j<4;j++){
      b0[j] = *(const short8*)(Bs[0] + bo + j*512);
      b1[j] = *(const short8*)(Bs[1] + bo + j*512);
    }
    __syncthreads();                       // reads done; LDS free for next stage
    int k1 = k0 + 64;
    if (k1 < K){
      #pragma unroll
      for (int s=0;s<2;s++){
        gl2lds(ap0 + k1 + s*32, As[s] + t*8);
        gl2lds(ap1 + k1 + s*32, As[s] + 2048 + t*8);
        gl2lds(bp0 + k1 + s*32, Bs[s] + t*8);
        gl2lds(bp1 + k1 + s*32, Bs[s] + 2048 + t*8);
      }
    }
    // k ascending: sub-slab 0 then sub-slab 1 (bit-identical to BK=32 order)
    #pragma unroll
    for (int i=0;i<4;i++)
      #pragma unroll
      for (int j=0;j<4;j++)
        acc[i][j] = mfma16(a0[i], b0[j], acc[i][j]);
    #pragma unroll
    for (int i=0;i<4;i++)
      #pragma unroll
      for (int j=0;j<4;j++)
        acc[i][j] = mfma16(a1[i], b1[j], acc[i][j]);
  }
}

// fused 2x2 split k-loop: stages Ah,Am,Bh,Bm once per k-chunk, accumulates
// hh + hm + mh in one pass; proven BK=32 2-phase register-prefetch schedule.
// (BK=64 here would need 64 KB LDS -> R5-style occupancy cliff; kept as-is.)
__device__ __forceinline__ void kloop2(const bf16* __restrict__ A0, const bf16* __restrict__ A1,
                                       int lda, int m0,
                                       const bf16* __restrict__ B0, const bf16* __restrict__ B1,
                                       int ldb, int n0, int K,
                                       bf16* As0, bf16* As1, bf16* Bs0, bf16* Bs1,
                                       f32x4 acc[4][4]){
  const int t = threadIdx.x;
  const int r = t>>2;
  const int sw = (t&3) ^ ((t>>3)&3);
  const long aoff0 = (long)(m0 + r)*lda + sw*8;
  const long aoff1 = (long)(m0 + 64 + r)*lda + sw*8;
  const long boff0 = (long)(n0 + r)*ldb + sw*8;
  const long boff1 = boff0 + (long)64*ldb;
  const int wave = t>>6, lane = t&63;
  const int qr = wave>>1, qc = wave&1, ln = lane&15, kq = lane>>4;
  const int slot = kq ^ ((ln>>1)&3);
  const int ao = (qr*64 + ln)*32 + slot*8;
  const int bo = (qc*64 + ln)*32 + slot*8;
  // prologue: stage k0 = 0
  gl2lds(A0 + aoff0, As0 + t*8);
  gl2lds(A0 + aoff1, As0 + 2048 + t*8);
  gl2lds(A1 + aoff0, As1 + t*8);
  gl2lds(A1 + aoff1, As1 + 2048 + t*8);
  gl2lds(B0 + boff0, Bs0 + t*8);
  gl2lds(B0 + boff1, Bs0 + 2048 + t*8);
  gl2lds(B1 + boff0, Bs1 + t*8);
  gl2lds(B1 + boff1, Bs1 + 2048 + t*8);
  for (int k0 = 0; k0 < K; k0 += 32){
    __syncthreads();
    short8 a0[4], a1[4], b0[4], b1[4];
    #pragma unroll
    for (int i=0;i<4;i++){
      a0[i] = *(const short8*)(As0 + ao + i*512);
      a1[i] = *(const short8*)(As1 + ao + i*512);
    }
    #pragma unroll
    for (int j=0;j<4;j++){
      b0[j] = *(const short8*)(Bs0 + bo + j*512);
      b1[j] = *(const short8*)(Bs1 + bo + j*512);
    }
    __syncthreads();
    int k1 = k0 + 32;
    if (k1 < K){
      gl2lds(A0 + aoff0 + k1, As0 + t*8);
      gl2lds(A0 + aoff1 + k1, As0 + 2048 + t*8);
      gl2lds(A1 + aoff0 + k1, As1 + t*8);
      gl2lds(A1 + aoff1 + k1, As1 + 2048 + t*8);
      gl2lds(B0 + boff0 + k1, Bs0 + t*8);
      gl2lds(B0 + boff1 + k1, Bs0 + 2048 + t*8);
      gl2lds(B1 + boff0 + k1, Bs1 + t*8);
      gl2lds(B1 + boff1 + k1, Bs1 + 2048 + t*8);
    }
    #pragma unroll
    for (int i=0;i<4;i++)
      #pragma unroll
      for (int j=0;j<4;j++){
        acc[i][j] = mfma16(a0[i], b0[j], acc[i][j]);
        acc[i][j] = mfma16(a0[i], b1[j], acc[i][j]);
        acc[i][j] = mfma16(a1[i], b0[j], acc[i][j]);
      }
  }
}

// fused 3x3 split k-loop (6 combos: hh, hm, mh, hl, mm, lh); 2-phase prefetch.
__device__ __forceinline__ void kloop3(const bf16* __restrict__ A0, const bf16* __restrict__ A1,
                                       const bf16* __restrict__ A2, int lda, int m0,
                                       const bf16* __restrict__ B0, const bf16* __restrict__ B1,
                                       const bf16* __restrict__ B2, int ldb, int n0, int K,
                                       bf16* As0, bf16* As1, bf16* As2,
                                       bf16* Bs0, bf16* Bs1, bf16* Bs2,
                                       f32x4 acc[4][4]){
  const int t = threadIdx.x;
  const int r = t>>2;
  const int sw = (t&3) ^ ((t>>3)&3);
  const long aoff0 = (long)(m0 + r)*lda + sw*8;
  const long aoff1 = (long)(m0 + 64 + r)*lda + sw*8;
  const long boff0 = (long)(n0 + r)*ldb + sw*8;
  const long boff1 = boff0 + (long)64*ldb;
  const int wave = t>>6, lane = t&63;
  const int qr = wave>>1, qc = wave&1, ln = lane&15, kq = lane>>4;
  const int slot = kq ^ ((ln>>1)&3);
  const int ao = (qr*64 + ln)*32 + slot*8;
  const int bo = (qc*64 + ln)*32 + slot*8;
  // prologue: stage k0 = 0
  gl2lds(A0 + aoff0, As0 + t*8);
  gl2lds(A0 + aoff1, As0 + 2048 + t*8);
  gl2lds(A1 + aoff0, As1 + t*8);
  gl2lds(A1 + aoff1, As1 + 2048 + t*8);
  gl2lds(A2 + aoff0, As2 + t*8);
  gl2lds(A2 + aoff1, As2 + 2048 + t*8);
  gl2lds(B0 + boff0, Bs0 + t*8);
  gl2lds(B0 + boff1, Bs0 + 2048 + t*8);
  gl2lds(B1 + boff0, Bs1 + t*8);
  gl2lds(B1 + boff1, Bs1 + 2048 + t*8);
  gl2lds(B2 + boff0, Bs2 + t*8);
  gl2lds(B2 + boff1, Bs2 + 2048 + t*8);
  for (int k0 = 0; k0 < K; k0 += 32){
    __syncthreads();
    short8 a0[4], a1[4], a2[4], b0[4], b1[4], b2[4];
    #pragma unroll
    for (int i=0;i<4;i++){
      a0[i] = *(const short8*)(As0 + ao + i*512);
      a1[i] = *(const short8*)(As1 + ao + i*512);
      a2[i] = *(const short8*)(As2 + ao + i*512);
    }
    #pragma unroll
    for (int j=0;j<4;j++){
      b0[j] = *(const short8*)(Bs0 + bo + j*512);
      b1[j] = *(const short8*)(Bs1 + bo + j*512);
      b2[j] = *(const short8*)(Bs2 + bo + j*512);
    }
    __syncthreads();
    int k1 = k0 + 32;
    if (k1 < K){
      gl2lds(A0 + aoff0 + k1, As0 + t*8);
      gl2lds(A0 + aoff1 + k1, As0 + 2048 + t*8);
      gl2lds(A1 + aoff0 + k1, As1 + t*8);
      gl2lds(A1 + aoff1 + k1, As1 + 2048 + t*8);
      gl2lds(A2 + aoff0 + k1, As2 + t*8);
      gl2lds(A2 + aoff1 + k1, As2 + 2048 + t*8);
      gl2lds(B0 + boff0 + k1, Bs0 + t*8);
      gl2lds(B0 + boff1 + k1, Bs0 + 2048 + t*8);
      gl2lds(B1 + boff0 + k1, Bs1 + t*8);
      gl2lds(B1 + boff1 + k1, Bs1 + 2048 + t*8);
      gl2lds(B2 + boff0 + k1, Bs2 + t*8);
      gl2lds(B2 + boff1 + k1, Bs2 + 2048 + t*8);
    }
    #pragma unroll
    for (int i=0;i<4;i++)
      #pragma unroll
      for (int j=0;j<4;j++){
        acc[i][j] = mfma16(a0[i], b0[j], acc[i][j]);
        acc[i][j] = mfma16(a0[i], b1[j], acc[i][j]);
        acc[i][j] = mfma16(a1[i], b0[j], acc[i][j]);
        acc[i][j] = mfma16(a0[i], b2[j], acc[i][j]);
        acc[i][j] = mfma16(a1[i], b1[j], acc[i][j]);
        acc[i][j] = mfma16(a2[i], b0[j], acc[i][j]);
      }
  }
}

#define EPI_SETUP \
  const int t = threadIdx.x, wave=t>>6, lane=t&63; \
  const int qr=wave>>1, qc=wave&1, ln=lane&15, kq=lane>>4; (void)qr;

#define ACC_INIT \
  f32x4 acc[4][4]; \
  _Pragma("unroll") for (int i=0;i<4;i++) _Pragma("unroll") for (int j=0;j<4;j++) \
    acc[i][j] = (f32x4){0.f,0.f,0.f,0.f};

// ================= fused prep (one launch) =================
// ol == nullptr skips the low-limb store (xl is never consumed downstream).
__device__ __forceinline__ void split3_body(const float* __restrict__ in,
    bf16* __restrict__ oh, bf16* __restrict__ om, bf16* __restrict__ ol, int b, int n4){
  int i = b*256 + threadIdx.x;
  if (i >= n4) return;
  float4 v = ((const float4*)in)[i];
  float vv[4] = {v.x, v.y, v.z, v.w};
  u16 hs[4], ms[4], ls[4];
  #pragma unroll
  for (int c=0;c<4;c++){
    bf16 h = __float2bfloat16(vv[c]); float r1 = vv[c] - __bfloat162float(h);
    bf16 m = __float2bfloat16(r1);    float r2 = r1 - __bfloat162float(m);
    bf16 l = __float2bfloat16(r2);
    hs[c]=*(u16*)&h; ms[c]=*(u16*)&m; ls[c]=*(u16*)&l;
  }
  ((ushort4*)oh)[i] = (ushort4){hs[0],hs[1],hs[2],hs[3]};
  ((ushort4*)om)[i] = (ushort4){ms[0],ms[1],ms[2],ms[3]};
  if (ol) ((ushort4*)ol)[i] = (ushort4){ls[0],ls[1],ls[2],ls[3]};
}

__device__ __forceinline__ void tsplit3_body(const float* __restrict__ in,
    bf16* __restrict__ oh, bf16* __restrict__ om, bf16* __restrict__ ol,
    int R, int C, int bx, int by, float* tile /*[64][65]*/){
  int r0 = by*64, c0 = bx*64;
  int t = threadIdx.x, lr = t>>4, lc = (t&15)*4;
  #pragma unroll
  for (int it=0; it<4; it++){
    int rr = it*16 + lr;
    float4 v = *(const float4*)(in + (long)(r0+rr)*C + c0 + lc);
    tile[rr*65+lc]=v.x; tile[rr*65+lc+1]=v.y; tile[rr*65+lc+2]=v.z; tile[rr*65+lc+3]=v.w;
  }
  __syncthreads();
  #pragma unroll
  for (int it=0; it<4; it++){
    int cc = it*16 + lr;
    u16 hs[4], ms[4], ls[4];
    #pragma unroll
    for (int j=0;j<4;j++){
      float v = tile[(lc+j)*65+cc];
      bf16 h = __float2bfloat16(v); float r1 = v - __bfloat162float(h);
      bf16 m = __float2bfloat16(r1); float r2 = r1 - __bfloat162float(m);
      bf16 l = __float2bfloat16(r2);
      hs[j]=*(u16*)&h; ms[j]=*(u16*)&m; ls[j]=*(u16*)&l;
    }
    long oi = (long)(c0+cc)*R + r0 + lc;
    *(ushort4*)((u16*)oh + oi) = (ushort4){hs[0],hs[1],hs[2],hs[3]};
    *(ushort4*)((u16*)om + oi) = (ushort4){ms[0],ms[1],ms[2],ms[3]};
    *(ushort4*)((u16*)ol + oi) = (ushort4){ls[0],ls[1],ls[2],ls[3]};
  }
}

__device__ __forceinline__ void cvtT_body(const float* __restrict__ in,
    bf16* __restrict__ out, int R, int C, int bx, int by, int bz, float* tile){
  long zb = (long)bz * R * C;
  int r0 = by*64, c0 = bx*64;
  int t = threadIdx.x, lr = t>>4, lc = (t&15)*4;
  #pragma unroll
  for (int it=0; it<4; it++){
    int rr = it*16 + lr;
    float4 v = *(const float4*)(in + zb + (long)(r0+rr)*C + c0 + lc);
    tile[rr*65+lc]=v.x; tile[rr*65+lc+1]=v.y; tile[rr*65+lc+2]=v.z; tile[rr*65+lc+3]=v.w;
  }
  __syncthreads();
  #pragma unroll
  for (int it=0; it<4; it++){
    int cc = it*16 + lr;
    u16 hs[4];
    #pragma unroll
    for (int j=0;j<4;j++){
      bf16 h = __float2bfloat16(tile[(lc+j)*65+cc]);
      hs[j]=*(u16*)&h;
    }
    *(ushort4*)((u16*)out + zb + (long)(c0+cc)*R + r0 + lc) = (ushort4){hs[0],hs[1],hs[2],hs[3]};
  }
}

__device__ __forceinline__ void cvec_body(const float* __restrict__ bmap,
    const float* __restrict__ Wr, const float* __restrict__ br, float* __restrict__ cvec, int b){
  int id = b*256 + threadIdx.x;   // (e,j)
  int e = id >> 9, j = id & 511;
  float s = 0.f;
  for (int k=0;k<512;k++) s += bmap[e*512+k] * Wr[k*512 + j];
  cvec[id] = s + br[j];
}

__global__ __launch_bounds__(256) void k_prep(const float* __restrict__ x,
    const float* __restrict__ Wmap, const float* __restrict__ Wr,
    const float* __restrict__ bmap, const float* __restrict__ br,
    const float* __restrict__ W1, const float* __restrict__ W2,
    const float* __restrict__ W3, const float* __restrict__ Wo,
    bf16* xh, bf16* xm,
    bf16* Wm_h, bf16* Wm_m, bf16* Wm_l,
    bf16* WrT_h, bf16* WrT_m, bf16* WrT_l, float* cvec,
    bf16* W1T, bf16* W2T, bf16* W3T, bf16* WoT){
  __shared__ float tile[64*65];
  int b = blockIdx.x;
  if (b < 2048){ split3_body(x, xh, xm, nullptr, b, 524288); return; }
  b -= 2048;
  if (b < 2048){ split3_body(Wmap, Wm_h, Wm_m, Wm_l, b, 524288); return; }
  b -= 2048;
  if (b < 64){ tsplit3_body(Wr, WrT_h, WrT_m, WrT_l, 512, 512, b&7, b>>3, tile); return; }
  b -= 64;
  if (b < 16){ cvec_body(bmap, Wr, br, cvec, b); return; }
  b -= 16;
  if (b < 1024){ cvtT_body(W1, W1T, 512, 1024, b&15, (b>>4)&7, b>>7, tile); return; }
  b -= 1024;
  if (b < 2048){ cvtT_body(W2, W2T, 1024, 1024, b&15, (b>>4)&15, b>>8, tile); return; }
  b -= 2048;
  if (b < 2048){ cvtT_body(W3, W3T, 1024, 1024, b&15, (b>>4)&15, b>>8, tile); return; }
  b -= 2048;
  cvtT_body(Wo, WoT, 1024, 512, b&7, b>>3, 0, tile);
}
#define PREP_BLOCKS 9424

// ---- MT_e[j,d] = sum_k Wr[k,j] * Wmap[d, e*512+k] — fused 6-combo single k-loop
__global__ __launch_bounds__(256) void k_gemm_MT(
    const bf16* __restrict__ Rh, const bf16* __restrict__ Rm, const bf16* __restrict__ Rl,
    const bf16* __restrict__ Wh, const bf16* __restrict__ Wm, const bf16* __restrict__ Wl,
    bf16* __restrict__ MTh, bf16* __restrict__ MTm, float* __restrict__ M32){
  __shared__ __align__(16) bf16 As0[4096], As1[4096], As2[4096],
                                Bs0[4096], Bs1[4096], Bs2[4096];
  int m0 = blockIdx.x*128, n0 = blockIdx.y*128, e = blockIdx.z;
  ACC_INIT
  kloop3(Rh, Rm, Rl, 512, m0, Wh + e*512, Wm + e*512, Wl + e*512, DE, n0, 512,
         As0, As1, As2, Bs0, Bs1, Bs2, acc);
  EPI_SETUP
  int cg[4];
  #pragma unroll
  for (int j=0;j<4;j++) cg[j] = n0 + qc*64 + j*16 + ln;
  long eb = (long)e*512*512;
  #pragma unroll
  for (int i=0;i<4;i++)
    #pragma unroll
    for (int r=0;r<4;r++){
      long base = eb + (long)(m0 + qr*64 + i*16 + kq*4 + r) * 512;
      #pragma unroll
      for (int j=0;j<4;j++){
        float v = acc[i][j][r];
        bf16 h = __float2bfloat16(v); float r1 = v - __bfloat162float(h);
        bf16 m = __float2bfloat16(r1);
        MTh[base + cg[j]] = h; MTm[base + cg[j]] = m; M32[base + cg[j]] = v;
      }
    }
}

// ---- re = x @ MT_e^T + c_e — fused 3-combo (hh+hm+mh) single k-loop;
// epilogue: dist2[n,e] += (x-re)^2 in fp64
__global__ __launch_bounds__(256) void k_gemm_re(
    const bf16* __restrict__ xh, const bf16* __restrict__ xm,
    const bf16* __restrict__ MTh, const bf16* __restrict__ MTm,
    const float* __restrict__ cvec, const float* __restrict__ x, double* __restrict__ dist2){
  __shared__ __align__(16) bf16 As0[4096], As1[4096], Bs0[4096], Bs1[4096];
  int m0 = blockIdx.x*128, n0 = blockIdx.y*128, e = blockIdx.z;
  ACC_INIT
  long eb = (long)e*512*512;
  kloop2(xh, xm, 512, m0, MTh + eb, MTm + eb, 512, n0, 512,
         As0, As1, Bs0, Bs1, acc);
  EPI_SETUP
  int cg[4]; float cv[4];
  #pragma unroll
  for (int j=0;j<4;j++){ cg[j] = n0 + qc*64 + j*16 + ln; cv[j] = cvec[e*512 + cg[j]]; }
  #pragma unroll
  for (int i=0;i<4;i++)
    #pragma unroll
    for (int r=0;r<4;r++){
      int rg = m0 + qr*64 + i*16 + kq*4 + r;      // token index
      const float* xr = x + (long)rg*512;
      double s = 0.0;
      #pragma unroll
      for (int j=0;j<4;j++){
        float re = acc[i][j][r] + cv[j];
        float d  = xr[cg[j]] - re;
        s += (double)d * (double)d;
      }
      s += __shfl_xor(s,1); s += __shfl_xor(s,2); s += __shfl_xor(s,4); s += __shfl_xor(s,8);
      if (ln == 0) atomicAdd(&dist2[(long)rg*EE + e], s);
    }
}

// ---- expert GEMM (ragged tile table, optional gather), gelu epilogue, fp32 bias
__global__ __launch_bounds__(256) void k_gemm_exp(const Tile* __restrict__ table,
    const bf16* __restrict__ A, int lda, const int* __restrict__ rowmap,
    const bf16* __restrict__ Wt, long wstride, int ldb, int K,
    const float* __restrict__ bias, int ncols, bf16* __restrict__ out, int ldo){
  Tile tc = table[blockIdx.x];
  if (tc.e < 0) return;
  __shared__ __align__(16) bf16 As[2][4096], Bs[2][4096];
  int n0 = blockIdx.y*128;
  ACC_INIT
  const bf16* BT = Wt + (long)tc.e*wstride;
  if (rowmap) kloop<true >(A, lda, rowmap, tc.row0, BT, ldb, n0, K, As, Bs, acc);
  else        kloop<false>(A, lda, nullptr, tc.row0, BT, ldb, n0, K, As, Bs, acc);
  EPI_SETUP
  const float* bp = bias + (long)tc.e*ncols;
  int cg[4]; float bv[4];
  #pragma unroll
  for (int j=0;j<4;j++){ cg[j] = n0 + qc*64 + j*16 + ln; bv[j] = bp[cg[j]]; }
  #pragma unroll
  for (int i=0;i<4;i++)
    #pragma unroll
    for (int r=0;r<4;r++){
      int rl = qr*64 + i*16 + kq*4 + r;
      if (rl < tc.rows){
        bf16* op = out + (long)(tc.row0 + rl)*ldo;
        #pragma unroll
        for (int j=0;j<4;j++)
          op[cg[j]] = __float2bfloat16(gelu_f(acc[i][j][r] + bv[j]));
      }
    }
}

// ---- out-proj GEMM: obuf = gelu(comb @ Wo + bo)
__global__ __launch_bounds__(256) void k_gemm_go(const bf16* __restrict__ A,
    const bf16* __restrict__ WoT, const float* __restrict__ bias, bf16* __restrict__ out){
  __shared__ __align__(16) bf16 As[2][4096], Bs[2][4096];
  int m0 = blockIdx.x*128, n0 = blockIdx.y*128;
  ACC_INIT
  kloop<false>(A, HH, nullptr, m0, WoT, HH, n0, HH, As, Bs, acc);
  EPI_SETUP
  int cg[4]; float bv[4];
  #pragma unroll
  for (int j=0;j<4;j++){ cg[j] = n0 + qc*64 + j*16 + ln; bv[j] = bias[cg[j]]; }
  #pragma unroll
  for (int i=0;i<4;i++)
    #pragma unroll
    for (int r=0;r<4;r++){
      long base = (long)(m0 + qr*64 + i*16 + kq*4 + r) * OUTD;
      #pragma unroll
      for (int j=0;j<4;j++)
        out[base + cg[j]] = __float2bfloat16(gelu_f(acc[i][j][r] + bv[j]));
    }
}

// ---- router select (fp64): top-2 LARGEST dist; flags low-margin tokens for rescue
__global__ __launch_bounds__(256) void k_select(const double* __restrict__ dist2,
    float* __restrict__ selp, int* __restrict__ seli, int* __restrict__ counts,
    float* __restrict__ entacc, int* __restrict__ flaglist, int* __restrict__ nflag){
  __shared__ int hc[EE];
  int t = threadIdx.x;
  if (t < EE) hc[t] = 0;
  __syncthreads();
  int n = blockIdx.x*256 + t;
  double d0 = -1.0, d1 = -1.0, d2 = -1.0; int i0 = 0, i1 = 0;
  #pragma unroll
  for (int e=0;e<EE;e++){
    double d = sqrt(dist2[(long)n*EE + e]);
    if (d > d0){ d2 = d1; d1 = d0; i1 = i0; d0 = d; i0 = e; }
    else if (d > d1){ d2 = d1; d1 = d; i1 = e; }
    else if (d > d2){ d2 = d; }
  }
  if (d1 - d2 < DMARGIN){ int p = atomicAdd(nflag, 1); flaglist[p & (FCAP-1)] = n; }
  double s0 = exp(-d0), s1 = exp(-d1);   // s0 = smallest sim -> slot 0
  double den = s0 + s1;
  float p0 = (float)(s0/den), p1 = (float)(s1/den);
  selp[2*n] = p0; selp[2*n+1] = p1;
  seli[2*n] = i0; seli[2*n+1] = i1;
  atomicAdd(&hc[i0], 1); atomicAdd(&hc[i1], 1);
  float a0 = p0, a1 = p1;
  float a2 = p0*logf(p0+1e-6f) + p1*logf(p1+1e-6f);
  #pragma unroll
  for (int m=32;m;m>>=1){ a0 += __shfl_down(a0,m); a1 += __shfl_down(a1,m); a2 += __shfl_down(a2,m); }
  if ((t&63)==0){ atomicAdd(&entacc[0], a0); atomicAdd(&entacc[1], a1); atomicAdd(&entacc[2], a2); }
  __syncthreads();
  if (t < EE) atomicAdd(&counts[t], hc[t]);
}

// ---- rescue: one (flagged-token, expert, j-chunk) work item per block iteration.
// Each pair is split over RSPLIT=4 blocks (128 rows each); each wave handles 32
// rows, batched 8 rows per shuffle-reduce round so 16 float4 loads are in flight
// at once. Partial sums land in rbuf4[pid*RSPLIT + chunk]; k_scan sums the chunks.
__global__ __launch_bounds__(256) void k_rescue(const int* __restrict__ flaglist,
    const int* __restrict__ nflag, const float* __restrict__ x,
    const float* __restrict__ M32, const float* __restrict__ cvec,
    double* __restrict__ rbuf4){
  __shared__ float xs[512];
  __shared__ double wsum[4];
  int t = threadIdx.x, w = t>>6, l = t&63;
  int nf = *nflag; if (nf > FCAP) nf = FCAP;
  int work = nf * EE * RSPLIT;
  for (int wid = blockIdx.x; wid < work; wid += gridDim.x){
    int pid = wid >> 2, chunk = wid & (RSPLIT-1);
    int f = pid >> 3, e = pid & 7;
    int n = flaglist[f];
    xs[t] = x[(long)n*512 + t]; xs[t+256] = x[(long)n*512 + 256 + t];
    __syncthreads();
    const float* Me = M32 + ((long)e << 18);
    const float* xp = xs + l*8;
    float x0=xp[0], x1=xp[1], x2=xp[2], x3=xp[3], x4=xp[4], x5=xp[5], x6=xp[6], x7=xp[7];
    double s = 0.0;
    int j0 = chunk*128 + w*32;
    for (int rb = 0; rb < 32; rb += 8){
      double d[8];
      #pragma unroll
      for (int rr=0; rr<8; rr++){
        const float* Mr = Me + (long)(j0 + rb + rr)*512 + l*8;
        float4 a = *(const float4*)Mr, b = *(const float4*)(Mr+4);
        d[rr] = (double)a.x*x0 + (double)a.y*x1 + (double)a.z*x2 + (double)a.w*x3
              + (double)b.x*x4 + (double)b.y*x5 + (double)b.z*x6 + (double)b.w*x7;
      }
      #pragma unroll
      for (int m=32;m;m>>=1){
        #pragma unroll
        for (int rr=0; rr<8; rr++) d[rr] += __shfl_down(d[rr], m);
      }
      if (l == 0){
        #pragma unroll
        for (int rr=0; rr<8; rr++){
          int j = j0 + rb + rr;
          double diff = (double)xs[j] - (d[rr] + (double)cvec[e*512 + j]);
          s += diff*diff;
        }
      }
    }
    if (l == 0) wsum[w] = s;
    __syncthreads();
    if (t == 0) rbuf4[wid] = wsum[0]+wsum[1]+wsum[2]+wsum[3];
    __syncthreads();
  }
}

// ---- merged: rescue patch (parallel) + tile-table scan (thread 0)
__global__ __launch_bounds__(256) void k_scan(const int* __restrict__ flaglist,
    const int* __restrict__ nflag, const double* __restrict__ rbuf4,
    float* __restrict__ selp, int* __restrict__ seli,
    int* __restrict__ counts, float* __restrict__ entacc,
    int* __restrict__ cursors, Tile* __restrict__ table, float* __restrict__ entout){
  int t = threadIdx.x;
  int nf = *nflag; if (nf > FCAP) nf = FCAP;
  for (int idx = t; idx < nf; idx += 256){
    int n = flaglist[idx];
    double d0=-1.0, d1=-1.0; int i0=0, i1=0;
    #pragma unroll
    for (int e=0;e<EE;e++){
      const double* rp = rbuf4 + ((long)(idx*EE + e))*RSPLIT;
      double d = sqrt(rp[0] + rp[1] + rp[2] + rp[3]);
      if (d > d0){ d1=d0; i1=i0; d0=d; i0=e; }
      else if (d > d1){ d1=d; i1=e; }
    }
    double s0 = exp(-d0), s1 = exp(-d1), den = s0+s1;
    float p0 = (float)(s0/den), p1 = (float)(s1/den);
    int o0 = seli[2*n], o1 = seli[2*n+1];
    float q0 = selp[2*n], q1 = selp[2*n+1];
    if (o0 != i0 || o1 != i1){
      atomicSub(&counts[o0], 1); atomicSub(&counts[o1], 1);
      atomicAdd(&counts[i0], 1); atomicAdd(&counts[i1], 1);
      seli[2*n] = i0; seli[2*n+1] = i1;
    }
    atomicAdd(&entacc[0], p0 - q0);
    atomicAdd(&entacc[1], p1 - q1);
    atomicAdd(&entacc[2], (p0*logf(p0+1e-6f) + p1*logf(p1+1e-6f))
                        - (q0*logf(q0+1e-6f) + q1*logf(q1+1e-6f)));
    selp[2*n] = p0; selp[2*n+1] = p1;
  }
  __threadfence();
  __syncthreads();
  if (t != 0) return;
  int off = 0, ti = 0;
  for (int e=0;e<EE;e++){
    cursors[e] = off;
    int c = counts[e];
    for (int r=0;r<c;r+=128){
      table[ti].e = e; table[ti].row0 = off + r;
      table[ti].rows = (c - r < 128) ? (c - r) : 128; ti++;
    }
    off += c;
  }
  for (; ti<MAXT; ti++){ table[ti].e = -1; table[ti].row0 = 0; table[ti].rows = 0; }
  float pm0 = entacc[0] * (1.0f/NTOK), pm1 = entacc[1] * (1.0f/NTOK);
  *entout = pm0*logf(pm0 + 1e-6f) + pm1*logf(pm1 + 1e-6f) - entacc[2] * (1.0f/NTOK);
}

__global__ __launch_bounds__(256) void k_place(const int* __restrict__ seli,
    const float* __restrict__ selp, int* __restrict__ cursors,
    int* __restrict__ atok, float* __restrict__ ap, int* __restrict__ aslot,
    int* __restrict__ aexp){
  int id = blockIdx.x*256 + threadIdx.x;   // 8192 = (token, slot)
  int e = seli[id];
  int pos = atomicAdd(&cursors[e], 1);
  atok[pos] = id >> 1;
  ap[pos]   = selp[id];
  aslot[pos]= id & 1;
  aexp[pos] = e;
}

__device__ __forceinline__ void blkred2(float& s, float& q, int t){
  #pragma unroll
  for (int m=32;m;m>>=1){ s += __shfl_down(s,m); q += __shfl_down(q,m); }
  __shared__ float shs[4], shq[4];
  if ((t&63)==0){ shs[t>>6] = s; shq[t>>6] = q; }
  __syncthreads();
  s = shs[0]+shs[1]+shs[2]+shs[3];
  q = shq[0]+shq[1]+shq[2]+shq[3];
}

// ---- LayerNorm over H=1024 per assignment row, per-expert fp32 gamma/beta
__global__ __launch_bounds__(256) void k_ln_mid(const bf16* __restrict__ in, bf16* __restrict__ out,
    const float* __restrict__ g, const float* __restrict__ be, const int* __restrict__ aexp){
  int row = blockIdx.x, t = threadIdx.x;
  const ushort4 u = *(const ushort4*)((const u16*)in + (long)row*HH + t*4);
  float v0=b2f(u.x), v1=b2f(u.y), v2=b2f(u.z), v3=b2f(u.w);
  float s = v0+v1+v2+v3;
  float q = v0*v0+v1*v1+v2*v2+v3*v3;
  blkred2(s, q, t);
  float mu = s*(1.0f/HH);
  float rs = rsqrtf(q*(1.0f/HH) - mu*mu + 1e-5f);
  int e = aexp[row];
  const float4 ug = *(const float4*)(g  + (long)e*HH + t*4);
  const float4 ub = *(const float4*)(be + (long)e*HH + t*4);
  bf16* op = out + (long)row*HH + t*4;
  op[0] = __float2bfloat16((v0-mu)*rs*ug.x + ub.x);
  op[1] = __float2bfloat16((v1-mu)*rs*ug.y + ub.y);
  op[2] = __float2bfloat16((v2-mu)*rs*ug.z + ub.z);
  op[3] = __float2bfloat16((v3-mu)*rs*ug.w + ub.w);
}

// ---- LN3 + gate multiply + scatter to per-slot fp32 buffer
__global__ __launch_bounds__(256) void k_ln3(const bf16* __restrict__ in, float* __restrict__ slots,
    const float* __restrict__ g, const float* __restrict__ be, const int* __restrict__ aexp,
    const int* __restrict__ atok, const int* __restrict__ aslot, const float* __restrict__ ap){
  int row = blockIdx.x, t = threadIdx.x;
  const ushort4 u = *(const ushort4*)((const u16*)in + (long)row*HH + t*4);
  float v0=b2f(u.x), v1=b2f(u.y), v2=b2f(u.z), v3=b2f(u.w);
  float s = v0+v1+v2+v3;
  float q = v0*v0+v1*v1+v2*v2+v3*v3;
  blkred2(s, q, t);
  float mu = s*(1.0f/HH);
  float rs = rsqrtf(q*(1.0f/HH) - mu*mu + 1e-5f);
  int e = aexp[row];
  const float4 ug = *(const float4*)(g  + (long)e*HH + t*4);
  const float4 ub = *(const float4*)(be + (long)e*HH + t*4);
  float p = ap[row];
  float* op = slots + ((long)atok[row]*2 + aslot[row])*HH + t*4;
  op[0] = p*((v0-mu)*rs*ug.x + ub.x);
  op[1] = p*((v1-mu)*rs*ug.y + ub.y);
  op[2] = p*((v2-mu)*rs*ug.z + ub.z);
  op[3] = p*((v3-mu)*rs*ug.w + ub.w);
}

// ---- combine: comb[n,c] = bf16(slots[n,0,c] + slots[n,1,c]) — float4 vectorized
__global__ __launch_bounds__(256) void k_comb(const float* __restrict__ slots, bf16* __restrict__ comb){
  long i = ((long)blockIdx.x*256 + threadIdx.x) * 4;
  long n = i >> 10, c = i & 1023;
  const float4 a = *(const float4*)(slots + n*2*HH + c);
  const float4 b = *(const float4*)(slots + (n*2+1)*HH + c);
  bf16 o0 = __float2bfloat16(a.x + b.x);
  bf16 o1 = __float2bfloat16(a.y + b.y);
  bf16 o2 = __float2bfloat16(a.z + b.z);
  bf16 o3 = __float2bfloat16(a.w + b.w);
  *(ushort4*)((u16*)comb + i) = (ushort4){*(u16*)&o0, *(u16*)&o1, *(u16*)&o2, *(u16*)&o3};
}

// ---- final LN over OUT=512 -> d_out (fp32); also writes ent_loss
__global__ __launch_bounds__(256) void k_lnout(const bf16* __restrict__ in, float* __restrict__ dout,
    const float* __restrict__ g, const float* __restrict__ be, const float* __restrict__ entout){
  int row = blockIdx.x, t = threadIdx.x;
  const bf16* ip = in + (long)row*OUTD + t*2;
  float v0 = __bfloat162float(ip[0]), v1 = __bfloat162float(ip[1]);
  float s = v0+v1, q = v0*v0+v1*v1;
  blkred2(s, q, t);
  float mu = s*(1.0f/OUTD);
  float rs = rsqrtf(q*(1.0f/OUTD) - mu*mu + 1e-5f);
  float g0 = g[t*2], g1v = g[t*2+1];
  float b0 = be[t*2], b1v = be[t*2+1];
  float* op = dout + (long)row*OUTD + t*2;
  op[0] = (v0-mu)*rs*g0 + b0;
  op[1] = (v1-mu)*rs*g1v + b1v;
  if (row==0 && t==0) dout[(long)NTOK*OUTD] = *entout;
}

extern "C" void kernel_launch(void* const* d_in, const int* in_sizes, int n_in,
                              void* d_out, int out_size, void* d_ws, size_t ws_size,
                              hipStream_t stream){
  (void)in_sizes; (void)n_in; (void)out_size; (void)ws_size;
  const float* x    = (const float*)d_in[0];
  const float* Wmap = (const float*)d_in[1];
  const float* bmap = (const float*)d_in[2];
  const float* Wr   = (const float*)d_in[3];
  const float* br   = (const float*)d_in[4];
  const float* W1   = (const float*)d_in[5];
  const float* b1   = (const float*)d_in[6];
  const float* g1   = (const float*)d_in[7];
  const float* be1  = (const float*)d_in[8];
  const float* W2   = (const float*)d_in[9];
  const float* b2   = (const float*)d_in[10];
  const float* g2   = (const float*)d_in[11];
  const float* be2  = (const float*)d_in[12];
  const float* W3   = (const float*)d_in[13];
  const float* b3   = (const float*)d_in[14];
  const float* g3   = (const float*)d_in[15];
  const float* be3  = (const float*)d_in[16];
  const float* Wo   = (const float*)d_in[17];
  const float* bo   = (const float*)d_in[18];
  const float* go   = (const float*)d_in[19];
  const float* beo  = (const float*)d_in[20];

  char* ws = (char*)d_ws;
  size_t o = 0;
  auto take = [&](size_t b){ size_t r = o; o += (b + 255) & ~(size_t)255; return r; };
  size_t o_xh   = take((size_t)NTOK*DD*2);     // bf16(x); also expert-GEMM1 A
  size_t o_xm   = take((size_t)NTOK*DD*2);     // comb overlays xm+xl
  size_t o_xl   = take((size_t)NTOK*DD*2);     // reserved (comb overlay); xl store skipped
  size_t o_R1   = take((size_t)APAD*HH*2);     // phase1: Wmap splits + WrT splits + cvec; phase2: hba
  size_t o_R2   = take((size_t)APAD*HH*2);     // phase1: MTh+MTm+M32;                    phase2: hbb
  size_t o_W1T  = take((size_t)EE*HH*DD*2);    // obuf overlays front half
  size_t o_W2T  = take((size_t)EE*HH*HH*2);    // slots overlays W2T+W3T (exactly 32 MB)
  size_t o_W3T  = take((size_t)EE*HH*HH*2);
  size_t o_WoT  = take((size_t)OUTD*HH*2);
  size_t o_dist2= take((size_t)NTOK*EE*8);     // zeroed (fp64)
  size_t o_cnt  = take(64);                    // zeroed
  size_t o_ent  = take(64);                    // zeroed
  size_t o_nfl  = take(64);                    // zeroed
  size_t o_cur  = take(64);
  size_t o_eout = take(64);
  size_t o_flag = take((size_t)FCAP*4);
  size_t o_rbuf = take((size_t)FCAP*EE*RSPLIT*8);
  size_t o_selp = take((size_t)NTOK*2*4);
  size_t o_seli = take((size_t)NTOK*2*4);
  size_t o_atok = take((size_t)ATOT*4);
  size_t o_ap   = take((size_t)ATOT*4);
  size_t o_aslt = take((size_t)ATOT*4);
  size_t o_aexp = take((size_t)ATOT*4);
  size_t o_tab  = take((size_t)MAXT*sizeof(Tile));
  (void)o_xl;

  bf16* xh=(bf16*)(ws+o_xh); bf16* xm=(bf16*)(ws+o_xm);
  // R1 sub-layout (phase 1)
  bf16* Wm_h=(bf16*)(ws+o_R1);
  bf16* Wm_m=(bf16*)(ws+o_R1+ 4194304);
  bf16* Wm_l=(bf16*)(ws+o_R1+ 8388608);
  bf16* WrT_h=(bf16*)(ws+o_R1+12582912);
  bf16* WrT_m=(bf16*)(ws+o_R1+13107200);
  bf16* WrT_l=(bf16*)(ws+o_R1+13631488);
  float* cvec=(float*)(ws+o_R1+14155776);
  // R2 sub-layout (phase 1): MTh (4MB) + MTm (4MB) + M32 fp32 (8MB) = 16MB <= 17MB
  bf16* MT_h=(bf16*)(ws+o_R2);
  bf16* MT_m=(bf16*)(ws+o_R2+4194304);
  float* M32=(float*)(ws+o_R2+8388608);
  // phase-2 overlays
  bf16* hba=(bf16*)(ws+o_R1);
  bf16* hbb=(bf16*)(ws+o_R2);
  bf16* W1T=(bf16*)(ws+o_W1T); bf16* W2T=(bf16*)(ws+o_W2T); bf16* W3T=(bf16*)(ws+o_W3T);
  bf16* WoT=(bf16*)(ws+o_WoT);
  float* slots=(float*)(ws+o_W2T);             // 32 MB = W2T+W3T
  bf16* comb=(bf16*)(ws+o_xm);                 // 8 MB = xm+xl
  bf16* obuf=(bf16*)(ws+o_W1T);                // 4 MB of W1T
  double* dist2=(double*)(ws+o_dist2);
  int* counts=(int*)(ws+o_cnt); float* entacc=(float*)(ws+o_ent);
  int* nflag=(int*)(ws+o_nfl);
  int* cursors=(int*)(ws+o_cur); float* entout=(float*)(ws+o_eout);
  int* flaglist=(int*)(ws+o_flag);
  double* rbuf4=(double*)(ws+o_rbuf);
  float* selp=(float*)(ws+o_selp); int* seli=(int*)(ws+o_seli);
  int* atok=(int*)(ws+o_atok); float* ap=(float*)(ws+o_ap);
  int* aslot=(int*)(ws+o_aslt); int* aexp=(int*)(ws+o_aexp);
  Tile* table=(Tile*)(ws+o_tab);

  hipMemsetAsync(ws + o_dist2, 0, (o_nfl + 64) - o_dist2, stream);

  // fused convert / split / transpose (one launch)
  k_prep<<<PREP_BLOCKS,256,0,stream>>>(x, Wmap, Wr, bmap, br, W1, W2, W3, Wo,
      xh, xm, Wm_h, Wm_m, Wm_l, WrT_h, WrT_m, WrT_l, cvec, W1T, W2T, W3T, WoT);

  // router
  k_gemm_MT<<<dim3(4,4,8),256,0,stream>>>(WrT_h, WrT_m, WrT_l, Wm_h, Wm_m, Wm_l,
                                          MT_h, MT_m, M32);
  k_gemm_re<<<dim3(32,4,8),256,0,stream>>>(xh, xm, MT_h, MT_m, cvec, x, dist2);
  k_select<<<16,256,0,stream>>>(dist2, selp, seli, counts, entacc, flaglist, nflag);
  k_rescue<<<2048,256,0,stream>>>(flaglist, nflag, x, M32, cvec, rbuf4);
  k_scan<<<1,256,0,stream>>>(flaglist, nflag, rbuf4, selp, seli, counts, entacc,
                             cursors, table, entout);
  k_place<<<32,256,0,stream>>>(seli, selp, cursors, atok, ap, aslot, aexp);

  // expert MLP (sparse, N*K = 8192 rows)
  k_gemm_exp<<<dim3(MAXT,8),256,0,stream>>>(table, xh, DD, atok,
      W1T, (long)HH*DD, DD, DD, b1, HH, hba, HH);
  k_ln_mid<<<ATOT,256,0,stream>>>(hba, hbb, g1, be1, aexp);
  k_gemm_exp<<<dim3(MAXT,8),256,0,stream>>>(table, hbb, HH, nullptr,
      W2T, (long)HH*HH, HH, HH, b2, HH, hba, HH);
  k_ln_mid<<<ATOT,256,0,stream>>>(hba, hbb, g2, be2, aexp);
  k_gemm_exp<<<dim3(MAXT,8),256,0,stream>>>(table, hbb, HH, nullptr,
      W3T, (long)HH*HH, HH, HH, b3, HH, hba, HH);
  k_ln3<<<ATOT,256,0,stream>>>(hba, slots, g3, be3, aexp, atok, aslot, ap);
  k_comb<<<4096,256,0,stream>>>(slots, comb);
  k_gemm_go<<<dim3(32,4),256,0,stream>>>(comb, WoT, bo, obuf);
  k_lnout<<<NTOK,256,0,stream>>>(obuf, (float*)d_out, go, beo, entout);
}